// Round 15
// baseline (1386.052 us; speedup 1.0000x reference)
//
#include <hip/hip_runtime.h>
#include <hip/hip_bf16.h>
#include <cstdint>

#define HID 128
#define NHEAD 4
#define NGRAPH 64
#define PCHUNK 32
#define MAXBINW 16384

typedef __attribute__((ext_vector_type(8))) short bf16x8;
typedef __attribute__((ext_vector_type(4))) short bf16x4s;
typedef __attribute__((ext_vector_type(4))) float f32x4;

__device__ __forceinline__ float bf2f(short u) {
    union { float f; unsigned int i; } c;
    c.i = ((unsigned int)(unsigned short)u) << 16;
    return c.f;
}
__device__ __forceinline__ float lrelu(float a) { return (a > 0.f) ? a : 0.2f * a; }

// ================= fused pre-pass: bincount + proj + castW + mkvec =================
struct PrePack {
    const int* edst[8]; int E[8]; int h_off[9]; int bsh[8];
    int* binCnt; // 64
    const float* px[4]; const float* pW[4]; const float* pb[4]; float* po[4];
    int pN[4]; int pK[4]; int p_off[5];
    const float* gat_W; __hip_bfloat16* Wsw;
    const float* gat_as; const float* gat_ad; float* vecall;
};

__global__ __launch_bounds__(256) void k_pre(PrePack A) {
    int b = blockIdx.x;
    int tid = threadIdx.x;
    if (b < A.h_off[8]) {
        __shared__ int h8[8];
        if (tid < 8) h8[tid] = 0;
        __syncthreads();
#pragma unroll
        for (int r = 0; r < 8; ++r) {
            if (b >= A.h_off[r] && b < A.h_off[r + 1]) {
                int e = (b - A.h_off[r]) * 256 + tid;
                if (e < A.E[r]) atomicAdd(&h8[A.edst[r][e] >> A.bsh[r]], 1);
                __syncthreads();
                if (tid < 8 && h8[tid] > 0) atomicAdd(&A.binCnt[r * 8 + tid], h8[tid]);
            }
        }
        return;
    }
    b -= A.h_off[8];
    if (b < A.p_off[4]) {
#pragma unroll
        for (int t = 0; t < 4; ++t) {
            if (b >= A.p_off[t] && b < A.p_off[t + 1]) {
                int idx = (b - A.p_off[t]) * 256 + tid;
                if (idx < A.pN[t] * HID) {
                    int row = idx >> 7, c = idx & 127;
                    int K = A.pK[t];
                    float acc = A.pb[t][c];
                    for (int k = 0; k < K; ++k) acc += A.px[t][row * K + k] * A.pW[t][k * HID + c];
                    A.po[t][idx] = acc;
                }
            }
        }
        return;
    }
    b -= A.p_off[4];
    if (b < 1024) {  // castW
        int idx = b * 256 + tid;
        int l = idx >> 17;
        int rem = idx & 131071;
        int k = rem >> 10;
        int gc = rem & 1023;
        int rel, n, gobase, Ncols;
        if (gc < 512) {
            int i = gc >> 7;
            rel = (i == 0) ? 0 : (i == 1) ? 2 : (i == 2) ? 4 : 5;
            n = gc; gobase = 0; Ncols = 512;
        } else if (gc < 768) {
            int c2 = gc - 512;
            rel = (c2 >> 7) ? 6 : 1;
            n = c2; gobase = 65536; Ncols = 256;
        } else {
            int c2 = gc - 768;
            rel = (c2 >> 7) ? 7 : 3;
            n = c2; gobase = 98304; Ncols = 256;
        }
        int nl = n & 127;
        float v = A.gat_W[(((size_t)l * 8 + rel) * 128 + k) * 128 + nl];
        size_t dst = (size_t)l * 131072 + gobase + ((size_t)(k >> 3) * Ncols + n) * 8 + (k & 7);
        A.Wsw[dst] = __float2bfloat16(v);
        return;
    }
    b -= 1024;
    {   // mkvec
        int idx = b * 256 + tid;
        if (idx < 16384) {
            int h = idx & 3, k = (idx >> 2) & 127, p = (idx >> 9) & 15, l = idx >> 13;
            int r = p >> 1, side = p & 1;
            const float* W = A.gat_W + (((size_t)l * 8 + r) * 128 + k) * 128;
            const float* a = (side ? A.gat_ad : A.gat_as) + ((size_t)l * 8 + r) * 128;
            float s = 0.f;
#pragma unroll
            for (int j = 0; j < 32; ++j) s += W[h * 32 + j] * a[h * 32 + j];
            A.vecall[((size_t)l * 16 + p) * 512 + k * 4 + h] = s;
        }
    }
}

// ================= binned CSR build (zero per-edge global atomics) =================
struct BinPack {
    const int* esrc[8]; const int* edst[8];
    uint2* staging[8];
    int* adj[8]; int* deg[8]; int* offs[8];
    int* binCnt; int* binBase; int* binCur;   // 64 ints each
    int E[8]; int Nd[8]; int binshift[8];
};

__global__ void k_binscan2(BinPack B) {
    int r = threadIdx.x;
    if (r >= 8) return;
    int run = 0;
    for (int b = 0; b < 8; ++b) {
        int c = B.binCnt[r * 8 + b];
        B.binBase[r * 8 + b] = run;
        B.binCur[r * 8 + b] = run;
        run += c;
    }
}

// phase 1: stage edges bin-contiguously (block-reserved runs, coalesced writes)
__global__ __launch_bounds__(256) void k_binp1(BinPack B) {
    int r = blockIdx.y;
    int E = B.E[r];
    int sh = B.binshift[r];
    __shared__ int h[8], base[8], rk[8];
    int tid = threadIdx.x;
    for (int e0 = blockIdx.x * 256; e0 < E; e0 += gridDim.x * 256) {
        if (tid < 8) { h[tid] = 0; rk[tid] = 0; }
        __syncthreads();
        int e = e0 + tid;
        int valid = e < E;
        int src = 0, dst = 0, bin = 0;
        if (valid) {
            src = B.esrc[r][e];
            dst = B.edst[r][e];
            bin = dst >> sh;
            atomicAdd(&h[bin], 1);
        }
        __syncthreads();
        if (tid < 8 && h[tid] > 0) base[tid] = atomicAdd(&B.binCur[r * 8 + tid], h[tid]);
        __syncthreads();
        if (valid) {
            int pos = base[bin] + atomicAdd(&rk[bin], 1);
            B.staging[r][pos] = make_uint2((unsigned)src, (unsigned)dst);
        }
        __syncthreads();
    }
}

// per-(rel,bin) LDS histogram -> deg slice (coalesced write, no memset needed)
__global__ __launch_bounds__(1024) void k_binhist(BinPack B) {
    int r = blockIdx.y, bin = blockIdx.x;
    int sh = B.binshift[r];
    int width = 1 << sh;
    int d0 = bin << sh;
    int Nd = B.Nd[r];
    int ndst = Nd - d0;
    if (ndst > width) ndst = width;
    __shared__ int h[MAXBINW];
    int tid = threadIdx.x;
    for (int i = tid; i < width; i += 1024) h[i] = 0;
    __syncthreads();
    if (ndst > 0) {
        int cnt = B.binCnt[r * 8 + bin];
        const uint2* st = B.staging[r] + B.binBase[r * 8 + bin];
        for (int i = tid; i < cnt; i += 1024) atomicAdd(&h[(int)st[i].y - d0], 1);
        __syncthreads();
        for (int i = tid; i < ndst; i += 1024) B.deg[r][d0 + i] = h[i];
    }
}

// per-(rel,bin) scatter with LDS curs (no global atomics); adj stores L2-resident
__global__ __launch_bounds__(1024) void k_binp2(BinPack B) {
    int r = blockIdx.y, bin = blockIdx.x;
    int sh = B.binshift[r];
    int width = 1 << sh;
    int d0 = bin << sh;
    int Nd = B.Nd[r];
    int ndst = Nd - d0;
    if (ndst > width) ndst = width;
    if (ndst <= 0) return;
    __shared__ int curs[MAXBINW];
    int tid = threadIdx.x;
    for (int i = tid; i < ndst; i += 1024) curs[i] = B.offs[r][d0 + i];
    __syncthreads();
    int cnt = B.binCnt[r * 8 + bin];
    const uint2* st = B.staging[r] + B.binBase[r * 8 + bin];
    int* adj = B.adj[r];
    for (int i = tid; i < cnt; i += 1024) {
        uint2 ed = st[i];
        int slot = atomicAdd(&curs[(int)ed.y - d0], 1);
        adj[slot] = (int)ed.x;
    }
}

// ================= CSR scans (deg -> offs) =================
struct ScanPack {
    int* deg[8];
    int* offs[8];
    int Nd[8];
};

__global__ void k_scan_part_all(ScanPack P, int* __restrict__ part_all) {
    int r = blockIdx.y;
    int N = P.Nd[r];
    if (blockIdx.x * 256 >= N) return;
    __shared__ int sh[256];
    int t = threadIdx.x, i = blockIdx.x * 256 + t;
    sh[t] = (i < N) ? P.deg[r][i] : 0;
    __syncthreads();
    for (int o = 128; o; o >>= 1) {
        if (t < o) sh[t] += sh[t + o];
        __syncthreads();
    }
    if (t == 0) part_all[r * 512 + blockIdx.x] = sh[0];
}
__global__ void k_scan_top_all(int* __restrict__ part_all, ScanPack P) {
    int r = blockIdx.x;
    int n = (P.Nd[r] + 255) / 256;
    __shared__ int sh[512];
    int t = threadIdx.x;
    int v = (t < n) ? part_all[r * 512 + t] : 0;
    sh[t] = v;
    __syncthreads();
    for (int o = 1; o < 512; o <<= 1) {
        int tmp = (t >= o) ? sh[t - o] : 0;
        __syncthreads();
        sh[t] += tmp;
        __syncthreads();
    }
    if (t < n) part_all[r * 512 + t] = sh[t] - v;
}
__global__ void k_scan_down_all(ScanPack P, const int* __restrict__ part_all) {
    int r = blockIdx.y;
    int N = P.Nd[r];
    if (blockIdx.x * 256 >= N) return;
    __shared__ int sh[256];
    int t = threadIdx.x, i = blockIdx.x * 256 + t;
    int v = (i < N) ? P.deg[r][i] : 0;
    sh[t] = v;
    __syncthreads();
    for (int o = 1; o < 256; o <<= 1) {
        int tmp = (t >= o) ? sh[t - o] : 0;
        __syncthreads();
        sh[t] += tmp;
        __syncthreads();
    }
    if (i < N) P.offs[r][i] = sh[t] - v + part_all[r * 512 + blockIdx.x];
}

// ================= fused mid pass: gemm || logits =================
__device__ __forceinline__ void gemm_body(char* smemraw, const float* __restrict__ A,
                                          const __hip_bfloat16* __restrict__ Bsw,
                                          __hip_bfloat16* __restrict__ out,
                                          int M, int Ncols, int bx, int by) {
    __hip_bfloat16 (*Alds)[136] = (__hip_bfloat16 (*)[136])smemraw;
    int m0 = bx * 64, n0 = by * 128;
    int t = threadIdx.x;
    for (int i = t; i < 2048; i += 256) {
        int row = i >> 5, ch = i & 31;
        float4 v = make_float4(0.f, 0.f, 0.f, 0.f);
        if (m0 + row < M) v = *(const float4*)(A + (size_t)(m0 + row) * 128 + ch * 4);
        __hip_bfloat16* dp = &Alds[row][ch * 4];
        dp[0] = __float2bfloat16(v.x);
        dp[1] = __float2bfloat16(v.y);
        dp[2] = __float2bfloat16(v.z);
        dp[3] = __float2bfloat16(v.w);
    }
    __syncthreads();
    int w = t >> 6, l = t & 63;
    int lane16 = l & 15, q = l >> 4;
    f32x4 acc[8];
#pragma unroll
    for (int nn = 0; nn < 8; ++nn) acc[nn] = (f32x4){0.f, 0.f, 0.f, 0.f};
    const __hip_bfloat16* arow = &Alds[w * 16 + lane16][q * 8];
#pragma unroll
    for (int kk = 0; kk < 4; ++kk) {
        bf16x8 a = *(const bf16x8*)(arow + kk * 32);
#pragma unroll
        for (int nn = 0; nn < 8; ++nn) {
            size_t boff = ((size_t)(kk * 4 + q) * Ncols + (n0 + nn * 16 + lane16)) * 8;
            bf16x8 b = *(const bf16x8*)(Bsw + boff);
            acc[nn] = __builtin_amdgcn_mfma_f32_16x16x32_bf16(a, b, acc[nn], 0, 0, 0);
        }
    }
    int orow = m0 + w * 16 + q * 4;
#pragma unroll
    for (int nn = 0; nn < 8; ++nn) {
        int col = n0 + nn * 16 + lane16;
#pragma unroll
        for (int r = 0; r < 4; ++r) {
            int row = orow + r;
            if (row < M) out[(size_t)row * Ncols + col] = __float2bfloat16(acc[nn][r]);
        }
    }
}

__device__ __forceinline__ void logits_body(char* smemraw,
                                            const float* const vec[7], float* const outp[7],
                                            const float* __restrict__ x, int N, int nv, int bloc) {
    float (*vs)[128][4] = (float (*)[128][4])smemraw;
    int t = threadIdx.x;
    for (int i = t; i < nv * 512; i += 256) {
        int v = i >> 9, j = i & 511;
        vs[v][j >> 2][j & 3] = vec[v][j];
    }
    __syncthreads();
    int nl = t >> 2, h = t & 3;
    int node = bloc * 64 + nl;
    if (node >= N) return;
    const float* xr = x + (size_t)node * 128;
    float acc[7];
#pragma unroll
    for (int v = 0; v < 7; ++v) acc[v] = 0.f;
#pragma unroll 4
    for (int k = 0; k < 128; ++k) {
        float xv = xr[k];
#pragma unroll
        for (int v = 0; v < 7; ++v)
            if (v < nv) acc[v] += xv * vs[v][k][h];
    }
#pragma unroll
    for (int v = 0; v < 7; ++v)
        if (v < nv) outp[v][node * 4 + h] = acc[v];
}

struct MidPack {
    const float* gA[3]; const __hip_bfloat16* gB[3]; __hip_bfloat16* gO[3];
    int gM[3]; int gNc[3]; int gMB[3]; int g_off[4];
    const float* lvec[4][7]; float* lout[4][7]; const float* lx[4];
    int lN[4]; int lnv[4]; int l_off[5];
};

__global__ __launch_bounds__(256) void k_mid(MidPack M) {
    __shared__ __align__(16) char smem[17408];
    int b = blockIdx.x;
    if (b < M.g_off[3]) {
#pragma unroll
        for (int g = 0; g < 3; ++g) {
            if (b >= M.g_off[g] && b < M.g_off[g + 1]) {
                int local = b - M.g_off[g];
                int bx = local % M.gMB[g];
                int by = local / M.gMB[g];
                gemm_body(smem, M.gA[g], M.gB[g], M.gO[g], M.gM[g], M.gNc[g], bx, by);
            }
        }
        return;
    }
    b -= M.g_off[3];
#pragma unroll
    for (int t = 0; t < 4; ++t) {
        if (b >= M.l_off[t] && b < M.l_off[t + 1]) {
            logits_body(smem, M.lvec[t], M.lout[t], M.lx[t], M.lN[t], M.lnv[t], b - M.l_off[t]);
        }
    }
}

// ================= fused per-dst GAT =================
struct RelArg {
    const __hip_bfloat16* hs;
    int hstride;
    int hoff;
    const float* als;
    const float* ald;
    const int* adj;
    const int* off;
    const int* deg;
    const float* bias;
};

__device__ __forceinline__ void dst_body(const RelArg& r0, const RelArg& r1, const RelArg& r2,
                                         int nrel, float inv_nrel, float* __restrict__ x,
                                         const float* __restrict__ ln_s,
                                         const float* __restrict__ ln_b, int N, int bloc) {
    int wv = threadIdx.x >> 6, lane = threadIdx.x & 63;
    int half = lane >> 5, sl = lane & 31;
    int d = bloc * 8 + wv * 2 + half;
    if (d >= N) return;
    int c0 = sl * 4;
    int h = sl >> 3;
    float4 xv = *(const float4*)&x[(size_t)d * HID + c0];
    float rel0 = 0.f, rel1 = 0.f, rel2 = 0.f, rel3 = 0.f;
    for (int rr = 0; rr < nrel; ++rr) {
        const RelArg& R = (rr == 0) ? r0 : (rr == 1) ? r1 : r2;
        int base = R.off[d];
        int dg = R.deg[d];
        float aldh = R.ald[d * NHEAD + h];
        const __hip_bfloat16* hp = R.hs + R.hoff + c0;
        const int hstr = R.hstride;
        const int* ap = R.adj + base;
        const float* als = R.als;
        float a0 = 0.f, a1 = 0.f, a2 = 0.f, a3 = 0.f, den = 0.f;
        int k = 0;
        for (; k + 4 <= dg; k += 4) {
            int s0 = ap[k], s1 = ap[k + 1], s2 = ap[k + 2], s3 = ap[k + 3];
            float w0 = __expf(lrelu(als[s0 * NHEAD + h] + aldh));
            float w1 = __expf(lrelu(als[s1 * NHEAD + h] + aldh));
            float w2 = __expf(lrelu(als[s2 * NHEAD + h] + aldh));
            float w3 = __expf(lrelu(als[s3 * NHEAD + h] + aldh));
            bf16x4s v0 = *(const bf16x4s*)(hp + (size_t)s0 * hstr);
            bf16x4s v1 = *(const bf16x4s*)(hp + (size_t)s1 * hstr);
            bf16x4s v2 = *(const bf16x4s*)(hp + (size_t)s2 * hstr);
            bf16x4s v3 = *(const bf16x4s*)(hp + (size_t)s3 * hstr);
            a0 += w0 * bf2f(v0[0]) + w1 * bf2f(v1[0]) + w2 * bf2f(v2[0]) + w3 * bf2f(v3[0]);
            a1 += w0 * bf2f(v0[1]) + w1 * bf2f(v1[1]) + w2 * bf2f(v2[1]) + w3 * bf2f(v3[1]);
            a2 += w0 * bf2f(v0[2]) + w1 * bf2f(v1[2]) + w2 * bf2f(v2[2]) + w3 * bf2f(v3[2]);
            a3 += w0 * bf2f(v0[3]) + w1 * bf2f(v1[3]) + w2 * bf2f(v2[3]) + w3 * bf2f(v3[3]);
            den += w0 + w1 + w2 + w3;
        }
        for (; k < dg; ++k) {
            int s = ap[k];
            float w = __expf(lrelu(als[s * NHEAD + h] + aldh));
            bf16x4s v = *(const bf16x4s*)(hp + (size_t)s * hstr);
            a0 += w * bf2f(v[0]);
            a1 += w * bf2f(v[1]);
            a2 += w * bf2f(v[2]);
            a3 += w * bf2f(v[3]);
            den += w;
        }
        float inv = 1.f / (den + 1e-16f);
        rel0 += a0 * inv + R.bias[c0];
        rel1 += a1 * inv + R.bias[c0 + 1];
        rel2 += a2 * inv + R.bias[c0 + 2];
        rel3 += a3 * inv + R.bias[c0 + 3];
    }
    float v0 = rel0 * inv_nrel, v1 = rel1 * inv_nrel;
    float v2 = rel2 * inv_nrel, v3 = rel3 * inv_nrel;
    v0 = (v0 > 0.f) ? v0 : 0.f;
    v1 = (v1 > 0.f) ? v1 : 0.f;
    v2 = (v2 > 0.f) ? v2 : 0.f;
    v3 = (v3 > 0.f) ? v3 : 0.f;
    v0 += xv.x; v1 += xv.y; v2 += xv.z; v3 += xv.w;
    float s = v0 + v1 + v2 + v3;
    float ss = v0 * v0 + v1 * v1 + v2 * v2 + v3 * v3;
#pragma unroll
    for (int o = 16; o; o >>= 1) {
        s += __shfl_xor(s, o);
        ss += __shfl_xor(ss, o);
    }
    float mu = s * (1.f / HID);
    float var = ss * (1.f / HID) - mu * mu;
    float rstd = rsqrtf(var + 1e-5f);
    float o0 = (v0 - mu) * rstd * ln_s[c0] + ln_b[c0];
    float o1 = (v1 - mu) * rstd * ln_s[c0 + 1] + ln_b[c0 + 1];
    float o2 = (v2 - mu) * rstd * ln_s[c0 + 2] + ln_b[c0 + 2];
    float o3 = (v3 - mu) * rstd * ln_s[c0 + 3] + ln_b[c0 + 3];
    *(float4*)&x[(size_t)d * HID + c0] = make_float4(o0, o1, o2, o3);
}

struct TypeArg {
    RelArg r0, r1, r2;
    float* x;
    int N;
    int nrel;
    float inv_nrel;
};

__global__ __launch_bounds__(256) void k_dst_all(TypeArg t0, TypeArg t1, TypeArg t2, TypeArg t3,
                                                 int off1, int off2, int off3,
                                                 const float* __restrict__ ln_s,
                                                 const float* __restrict__ ln_b) {
    int b = blockIdx.x;
    if (b < off1) {
        dst_body(t0.r0, t0.r1, t0.r2, t0.nrel, t0.inv_nrel, t0.x, ln_s, ln_b, t0.N, b);
    } else if (b < off2) {
        dst_body(t1.r0, t1.r1, t1.r2, t1.nrel, t1.inv_nrel, t1.x, ln_s, ln_b, t1.N, b - off1);
    } else if (b < off3) {
        dst_body(t2.r0, t2.r1, t2.r2, t2.nrel, t2.inv_nrel, t2.x, ln_s, ln_b, t2.N, b - off2);
    } else {
        dst_body(t3.r0, t3.r1, t3.r2, t3.nrel, t3.inv_nrel, t3.x, ln_s, ln_b, t3.N, b - off3);
    }
}

// ================= pooling =================
__global__ void k_pool_all(const float* __restrict__ x0, const float* __restrict__ x1,
                           const float* __restrict__ x2, const float* __restrict__ x3,
                           const int* __restrict__ b0, const int* __restrict__ b1,
                           const int* __restrict__ b2, const int* __restrict__ b3,
                           int N0, int N1, int N2, int N3, float* __restrict__ out) {
    int ty = blockIdx.y;
    const float* x;
    const int* b;
    int N, toff;
    if (ty == 0)      { x = x0; b = b0; N = N0; toff = 0; }
    else if (ty == 1) { x = x1; b = b1; N = N1; toff = 128; }
    else if (ty == 2) { x = x2; b = b2; N = N2; toff = 256; }
    else              { x = x3; b = b3; N = N3; toff = 384; }
    int r0 = blockIdx.x * PCHUNK;
    if (r0 >= N) return;
    int rend = min(r0 + PCHUNK, N);
    int c = threadIdx.x;
    int cur = b[r0];
    float acc = 0.f;
    for (int i = r0; i < rend; ++i) {
        int g = b[i];
        if (g != cur) {
            atomicAdd(&out[cur * 512 + toff + c], acc);
            acc = 0.f;
            cur = g;
        }
        acc += x[(size_t)i * HID + c];
    }
    atomicAdd(&out[cur * 512 + toff + c], acc);
}
__global__ void k_cnt(const int* __restrict__ b0, const int* __restrict__ b1,
                      const int* __restrict__ b2, const int* __restrict__ b3,
                      int N0, int N1, int N2, int N3, float* __restrict__ cnt) {
    int i = blockIdx.x * blockDim.x + threadIdx.x;
    if (i >= 256) return;
    int t = i >> 6, g = i & 63;
    const int* b = (t == 0) ? b0 : (t == 1) ? b1 : (t == 2) ? b2 : b3;
    int N = (t == 0) ? N0 : (t == 1) ? N1 : (t == 2) ? N2 : N3;
    int lo = 0, hi = N;
    while (lo < hi) { int m = (lo + hi) >> 1; if (b[m] < g) lo = m + 1; else hi = m; }
    int s = lo;
    hi = N;
    while (lo < hi) { int m = (lo + hi) >> 1; if (b[m] < g + 1) lo = m + 1; else hi = m; }
    cnt[i] = (float)(lo - s);
}
__global__ void k_div(float* __restrict__ out, const float* __restrict__ cnt) {
    int idx = blockIdx.x * blockDim.x + threadIdx.x;
    if (idx >= NGRAPH * 512) return;
    int g = idx >> 9, c = idx & 511, t = c >> 7;
    out[idx] = out[idx] / fmaxf(cnt[t * NGRAPH + g], 1.0f);
}

extern "C" void kernel_launch(void* const* d_in, const int* in_sizes, int n_in,
                              void* d_out, int out_size, void* d_ws, size_t ws_size,
                              hipStream_t stream) {
    const float* x_in[4] = {(const float*)d_in[0], (const float*)d_in[1],
                            (const float*)d_in[2], (const float*)d_in[3]};
    const float* Wp[4] = {(const float*)d_in[4], (const float*)d_in[6],
                          (const float*)d_in[8], (const float*)d_in[10]};
    const float* bp[4] = {(const float*)d_in[5], (const float*)d_in[7],
                          (const float*)d_in[9], (const float*)d_in[11]};
    const float* gat_W  = (const float*)d_in[12];
    const float* gat_as = (const float*)d_in[13];
    const float* gat_ad = (const float*)d_in[14];
    const float* gat_b  = (const float*)d_in[15];
    const float* ln_s   = (const float*)d_in[16];
    const float* ln_b   = (const float*)d_in[17];
    const int* esrc[8] = {(const int*)d_in[18], (const int*)d_in[20], (const int*)d_in[22],
                          (const int*)d_in[24], (const int*)d_in[26], (const int*)d_in[28],
                          (const int*)d_in[30], (const int*)d_in[32]};
    const int* edst[8] = {(const int*)d_in[19], (const int*)d_in[21], (const int*)d_in[23],
                          (const int*)d_in[25], (const int*)d_in[27], (const int*)d_in[29],
                          (const int*)d_in[31], (const int*)d_in[33]};
    const int* bidx[4] = {(const int*)d_in[34], (const int*)d_in[35],
                          (const int*)d_in[36], (const int*)d_in[37]};
    int E[8];
    {
        const int eidx[8] = {18, 20, 22, 24, 26, 28, 30, 32};
        for (int r = 0; r < 8; ++r) E[r] = in_sizes[eidx[r]];
    }
    const int Kin[4] = {8, 10, 7, 3};
    int N[4];
    for (int t = 0; t < 4; ++t) N[t] = in_sizes[t] / Kin[t];
    const int rel_st[8] = {0, 1, 0, 2, 0, 0, 1, 2};
    const int rel_dt[8] = {1, 0, 2, 0, 3, 0, 3, 3};
    const int rel_hoff[8] = {0, 0, 128, 0, 256, 384, 128, 128};
    const int grp_stride[4] = {512, 256, 256, 0};
    (void)ws_size; (void)n_in;

    // ---- workspace ----
    char* wbase = (char*)d_ws;
    size_t cur = 0;
    auto alloc = [&](size_t bytes) -> void* {
        void* p = wbase + cur;
        cur += (bytes + 15) & ~(size_t)15;
        return p;
    };
    float* x[4];
    for (int t = 0; t < 4; ++t) x[t] = (float*)alloc((size_t)N[t] * HID * 4);
    __hip_bfloat16* hs_g[3];
    hs_g[0] = (__hip_bfloat16*)alloc((size_t)N[0] * 512 * 2);
    hs_g[1] = (__hip_bfloat16*)alloc((size_t)N[1] * 256 * 2);
    hs_g[2] = (__hip_bfloat16*)alloc((size_t)N[2] * 256 * 2);
    __hip_bfloat16* Wsw = (__hip_bfloat16*)alloc((size_t)2 * 131072 * 2);
    float* vecall = (float*)alloc((size_t)2 * 16 * 512 * 4);
    float *als_[8], *ald_[8];
    int *deg[8], *offs[8], *adj[8];
    uint2* staging[8];
    for (int r = 0; r < 8; ++r) {
        int Ns = N[rel_st[r]], Nd = N[rel_dt[r]];
        als_[r] = (float*)alloc((size_t)Ns * NHEAD * 4);
        ald_[r] = (float*)alloc((size_t)Nd * NHEAD * 4);
        deg[r]  = (int*)alloc((size_t)Nd * 4);
        offs[r] = (int*)alloc((size_t)Nd * 4);
        adj[r]  = (int*)alloc((size_t)E[r] * 4);
        staging[r] = (uint2*)alloc((size_t)E[r] * 8);
    }
    int* part_all = (int*)alloc(8 * 512 * 4);
    int* binCnt   = (int*)alloc(64 * 4);
    int* binBase  = (int*)alloc(64 * 4);
    int* binCur   = (int*)alloc(64 * 4);
    float* cntf   = (float*)alloc(256 * 4);

    // ---- packs ----
    BinPack BP;
    int NdMax = 0;
    for (int r = 0; r < 8; ++r) {
        BP.esrc[r] = esrc[r]; BP.edst[r] = edst[r];
        BP.staging[r] = staging[r];
        BP.adj[r] = adj[r]; BP.deg[r] = deg[r]; BP.offs[r] = offs[r];
        BP.E[r] = E[r]; BP.Nd[r] = N[rel_dt[r]];
        int sh = 8;
        while (((BP.Nd[r] - 1) >> sh) > 7) ++sh;
        BP.binshift[r] = sh;
        if (BP.Nd[r] > NdMax) NdMax = BP.Nd[r];
    }
    BP.binCnt = binCnt; BP.binBase = binBase; BP.binCur = binCur;
    ScanPack SP;
    for (int r = 0; r < 8; ++r) { SP.deg[r] = deg[r]; SP.offs[r] = offs[r]; SP.Nd[r] = BP.Nd[r]; }

    // ---- 0a. memset binCnt + fused pre-pass ----
    hipMemsetAsync(binCnt, 0, 64 * 4, stream);
    PrePack PA;
    {
        for (int r = 0; r < 8; ++r) { PA.edst[r] = edst[r]; PA.E[r] = E[r]; PA.bsh[r] = BP.binshift[r]; }
        PA.binCnt = binCnt;
        PA.h_off[0] = 0;
        for (int r = 0; r < 8; ++r) PA.h_off[r + 1] = PA.h_off[r] + (E[r] + 255) / 256;
        for (int t = 0; t < 4; ++t) {
            PA.px[t] = x_in[t]; PA.pW[t] = Wp[t]; PA.pb[t] = bp[t]; PA.po[t] = x[t];
            PA.pN[t] = N[t]; PA.pK[t] = Kin[t];
        }
        PA.p_off[0] = 0;
        for (int t = 0; t < 4; ++t) PA.p_off[t + 1] = PA.p_off[t] + (N[t] * HID + 255) / 256;
        PA.gat_W = gat_W; PA.Wsw = Wsw;
        PA.gat_as = gat_as; PA.gat_ad = gat_ad; PA.vecall = vecall;
        int total = PA.h_off[8] + PA.p_off[4] + 1024 + 64;
        k_pre<<<total, 256, 0, stream>>>(PA);
    }

    // ---- 0b. bin scan -> stage -> LDS hist -> scans -> LDS scatter ----
    {
        k_binscan2<<<1, 64, 0, stream>>>(BP);
        dim3 g1(512, 8);
        k_binp1<<<g1, 256, 0, stream>>>(BP);
        dim3 gb(8, 8);
        k_binhist<<<gb, 1024, 0, stream>>>(BP);
        dim3 gn((NdMax + 255) / 256, 8);
        k_scan_part_all<<<gn, 256, 0, stream>>>(SP, part_all);
        k_scan_top_all<<<8, 512, 0, stream>>>(part_all, SP);
        k_scan_down_all<<<gn, 256, 0, stream>>>(SP, part_all);
        k_binp2<<<gb, 1024, 0, stream>>>(BP);
    }

    // ---- independent: counts + out zero ----
    hipMemsetAsync(d_out, 0, (size_t)out_size * 4, stream);
    k_cnt<<<1, 256, 0, stream>>>(bidx[0], bidx[1], bidx[2], bidx[3],
                                 N[0], N[1], N[2], N[3], cntf);

    // ---- layers ----
    const size_t g_woff[3] = {0, 65536, 98304};
    const int g_ncols[3] = {512, 256, 256};
    int nb[4];
    for (int t = 0; t < 4; ++t) nb[t] = (N[t] + 7) / 8;
    int doff1 = nb[0], doff2 = nb[0] + nb[1], doff3 = nb[0] + nb[1] + nb[2];
    int dtot = doff3 + nb[3];

    for (int l = 0; l < 2; ++l) {
        MidPack M;
        M.g_off[0] = 0;
        for (int g = 0; g < 3; ++g) {
            M.gA[g] = x[g];
            M.gB[g] = Wsw + (size_t)l * 131072 + g_woff[g];
            M.gO[g] = hs_g[g];
            M.gM[g] = N[g];
            M.gNc[g] = g_ncols[g];
            M.gMB[g] = (N[g] + 63) / 64;
            M.g_off[g + 1] = M.g_off[g] + M.gMB[g] * (g_ncols[g] / 128);
        }
        const float* vl = vecall + (size_t)l * 16 * 512;
        auto vvec = [&](int r, int side) { return vl + (size_t)(r * 2 + side) * 512; };
        for (int t = 0; t < 4; ++t)
            for (int v = 0; v < 7; ++v) { M.lvec[t][v] = vl; M.lout[t][v] = als_[0]; }
        M.lvec[0][0] = vvec(0, 0); M.lout[0][0] = als_[0];
        M.lvec[0][1] = vvec(2, 0); M.lout[0][1] = als_[2];
        M.lvec[0][2] = vvec(4, 0); M.lout[0][2] = als_[4];
        M.lvec[0][3] = vvec(5, 0); M.lout[0][3] = als_[5];
        M.lvec[0][4] = vvec(1, 1); M.lout[0][4] = ald_[1];
        M.lvec[0][5] = vvec(3, 1); M.lout[0][5] = ald_[3];
        M.lvec[0][6] = vvec(5, 1); M.lout[0][6] = ald_[5];
        M.lvec[1][0] = vvec(1, 0); M.lout[1][0] = als_[1];
        M.lvec[1][1] = vvec(6, 0); M.lout[1][1] = als_[6];
        M.lvec[1][2] = vvec(0, 1); M.lout[1][2] = ald_[0];
        M.lvec[2][0] = vvec(3, 0); M.lout[2][0] = als_[3];
        M.lvec[2][1] = vvec(7, 0); M.lout[2][1] = als_[7];
        M.lvec[2][2] = vvec(2, 1); M.lout[2][2] = ald_[2];
        M.lvec[3][0] = vvec(4, 1); M.lout[3][0] = ald_[4];
        M.lvec[3][1] = vvec(6, 1); M.lout[3][1] = ald_[6];
        M.lvec[3][2] = vvec(7, 1); M.lout[3][2] = ald_[7];
        const int lnv[4] = {7, 3, 3, 3};
        M.l_off[0] = 0;
        for (int t = 0; t < 4; ++t) {
            M.lx[t] = x[t]; M.lN[t] = N[t]; M.lnv[t] = lnv[t];
            M.l_off[t + 1] = M.l_off[t] + (N[t] + 63) / 64;
        }
        int total = M.g_off[3] + M.l_off[4];
        k_mid<<<total, 256, 0, stream>>>(M);

        auto mk = [&](int r) {
            RelArg a;
            int st = rel_st[r];
            a.hs = hs_g[st]; a.hstride = grp_stride[st]; a.hoff = rel_hoff[r];
            a.als = als_[r]; a.ald = ald_[r];
            a.adj = adj[r]; a.off = offs[r]; a.deg = deg[r];
            a.bias = gat_b + (size_t)(l * 8 + r) * HID;
            return a;
        };
        TypeArg T[4];
        const int trels[4][3] = {{1, 3, 5}, {0, 0, 0}, {2, 2, 2}, {4, 6, 7}};
        const int tnrel[4] = {3, 1, 1, 3};
        const float tinv[4] = {1.f / 3.f, 1.f, 1.f, 1.f / 3.f};
        for (int t = 0; t < 4; ++t) {
            T[t].r0 = mk(trels[t][0]);
            T[t].r1 = mk(trels[t][1]);
            T[t].r2 = mk(trels[t][2]);
            T[t].x = x[t];
            T[t].N = N[t];
            T[t].nrel = tnrel[t];
            T[t].inv_nrel = tinv[t];
        }
        k_dst_all<<<dtot, 256, 0, stream>>>(T[0], T[1], T[2], T[3], doff1, doff2, doff3,
                                            ln_s + l * HID, ln_b + l * HID);
    }

    // ---- pooling ----
    {
        int pmax = 0;
        for (int t = 0; t < 4; ++t) {
            int p = (N[t] + PCHUNK - 1) / PCHUNK;
            if (p > pmax) pmax = p;
        }
        dim3 gp(pmax, 4);
        k_pool_all<<<gp, 128, 0, stream>>>(x[0], x[1], x[2], x[3],
                                           bidx[0], bidx[1], bidx[2], bidx[3],
                                           N[0], N[1], N[2], N[3], (float*)d_out);
    }
    k_div<<<(NGRAPH * 512 + 255) / 256, 256, 0, stream>>>((float*)d_out, cntf);
}

// Round 16
// 1179.393 us; speedup vs baseline: 1.1752x; 1.1752x over previous
//
#include <hip/hip_runtime.h>
#include <hip/hip_bf16.h>
#include <cstdint>

#define HID 128
#define NHEAD 4
#define NGRAPH 64
#define PCHUNK 32
#define NBIN 64
#define MAXBINW 2048

typedef __attribute__((ext_vector_type(8))) short bf16x8;
typedef __attribute__((ext_vector_type(4))) short bf16x4s;
typedef __attribute__((ext_vector_type(4))) float f32x4;

__device__ __forceinline__ float bf2f(short u) {
    union { float f; unsigned int i; } c;
    c.i = ((unsigned int)(unsigned short)u) << 16;
    return c.f;
}
__device__ __forceinline__ float lrelu(float a) { return (a > 0.f) ? a : 0.2f * a; }

// ================= fused pre-pass: bincount + proj + castW + mkvec =================
struct PrePack {
    const int* edst[8]; int E[8]; int h_off[9]; int bsh[8];
    int* binCnt; // 8*NBIN
    const float* px[4]; const float* pW[4]; const float* pb[4]; float* po[4];
    int pN[4]; int pK[4]; int p_off[5];
    const float* gat_W; __hip_bfloat16* Wsw;
    const float* gat_as; const float* gat_ad; float* vecall;
};

__global__ __launch_bounds__(256) void k_pre(PrePack A) {
    int b = blockIdx.x;
    int tid = threadIdx.x;
    if (b < A.h_off[8]) {
        __shared__ int h64[NBIN];
        if (tid < NBIN) h64[tid] = 0;
        __syncthreads();
#pragma unroll
        for (int r = 0; r < 8; ++r) {
            if (b >= A.h_off[r] && b < A.h_off[r + 1]) {
                int e = (b - A.h_off[r]) * 256 + tid;
                if (e < A.E[r]) atomicAdd(&h64[A.edst[r][e] >> A.bsh[r]], 1);
                __syncthreads();
                if (tid < NBIN && h64[tid] > 0) atomicAdd(&A.binCnt[r * NBIN + tid], h64[tid]);
            }
        }
        return;
    }
    b -= A.h_off[8];
    if (b < A.p_off[4]) {
#pragma unroll
        for (int t = 0; t < 4; ++t) {
            if (b >= A.p_off[t] && b < A.p_off[t + 1]) {
                int idx = (b - A.p_off[t]) * 256 + tid;
                if (idx < A.pN[t] * HID) {
                    int row = idx >> 7, c = idx & 127;
                    int K = A.pK[t];
                    float acc = A.pb[t][c];
                    for (int k = 0; k < K; ++k) acc += A.px[t][row * K + k] * A.pW[t][k * HID + c];
                    A.po[t][idx] = acc;
                }
            }
        }
        return;
    }
    b -= A.p_off[4];
    if (b < 1024) {  // castW
        int idx = b * 256 + tid;
        int l = idx >> 17;
        int rem = idx & 131071;
        int k = rem >> 10;
        int gc = rem & 1023;
        int rel, n, gobase, Ncols;
        if (gc < 512) {
            int i = gc >> 7;
            rel = (i == 0) ? 0 : (i == 1) ? 2 : (i == 2) ? 4 : 5;
            n = gc; gobase = 0; Ncols = 512;
        } else if (gc < 768) {
            int c2 = gc - 512;
            rel = (c2 >> 7) ? 6 : 1;
            n = c2; gobase = 65536; Ncols = 256;
        } else {
            int c2 = gc - 768;
            rel = (c2 >> 7) ? 7 : 3;
            n = c2; gobase = 98304; Ncols = 256;
        }
        int nl = n & 127;
        float v = A.gat_W[(((size_t)l * 8 + rel) * 128 + k) * 128 + nl];
        size_t dst = (size_t)l * 131072 + gobase + ((size_t)(k >> 3) * Ncols + n) * 8 + (k & 7);
        A.Wsw[dst] = __float2bfloat16(v);
        return;
    }
    b -= 1024;
    {   // mkvec
        int idx = b * 256 + tid;
        if (idx < 16384) {
            int h = idx & 3, k = (idx >> 2) & 127, p = (idx >> 9) & 15, l = idx >> 13;
            int r = p >> 1, side = p & 1;
            const float* W = A.gat_W + (((size_t)l * 8 + r) * 128 + k) * 128;
            const float* a = (side ? A.gat_ad : A.gat_as) + ((size_t)l * 8 + r) * 128;
            float s = 0.f;
#pragma unroll
            for (int j = 0; j < 32; ++j) s += W[h * 32 + j] * a[h * 32 + j];
            A.vecall[((size_t)l * 16 + p) * 512 + k * 4 + h] = s;
        }
    }
}

// ================= binned CSR build (zero per-edge global atomics) =================
struct BinPack {
    const int* esrc[8]; const int* edst[8];
    uint2* staging[8];
    int* adj[8]; int* deg[8]; int* offs[8];
    int* binCnt; int* binBase; int* binCur;   // 8*NBIN ints each
    int E[8]; int Nd[8]; int binshift[8];
};

__global__ void k_binscan2(BinPack B) {
    int r = threadIdx.x;
    if (r >= 8) return;
    int run = 0;
    for (int b = 0; b < NBIN; ++b) {
        int c = B.binCnt[r * NBIN + b];
        B.binBase[r * NBIN + b] = run;
        B.binCur[r * NBIN + b] = run;
        run += c;
    }
}

// phase 1: stage edges bin-contiguously (block-reserved runs, coalesced-ish writes)
__global__ __launch_bounds__(256) void k_binp1(BinPack B) {
    int r = blockIdx.y;
    int E = B.E[r];
    int sh = B.binshift[r];
    __shared__ int h[NBIN], base[NBIN], rk[NBIN];
    int tid = threadIdx.x;
    for (int e0 = blockIdx.x * 256; e0 < E; e0 += gridDim.x * 256) {
        if (tid < NBIN) { h[tid] = 0; rk[tid] = 0; }
        __syncthreads();
        int e = e0 + tid;
        int valid = e < E;
        int src = 0, dst = 0, bin = 0;
        if (valid) {
            src = B.esrc[r][e];
            dst = B.edst[r][e];
            bin = dst >> sh;
            atomicAdd(&h[bin], 1);
        }
        __syncthreads();
        if (tid < NBIN && h[tid] > 0) base[tid] = atomicAdd(&B.binCur[r * NBIN + tid], h[tid]);
        __syncthreads();
        if (valid) {
            int pos = base[bin] + atomicAdd(&rk[bin], 1);
            B.staging[r][pos] = make_uint2((unsigned)src, (unsigned)dst);
        }
        __syncthreads();
    }
}

// per-(rel,bin) LDS histogram -> deg slice (coalesced write, replaces memset+global hist)
__global__ __launch_bounds__(1024) void k_binhist(BinPack B) {
    int r = blockIdx.y, bin = blockIdx.x;
    int sh = B.binshift[r];
    int width = 1 << sh;
    int d0 = bin << sh;
    int Nd = B.Nd[r];
    int ndst = Nd - d0;
    if (ndst > width) ndst = width;
    if (ndst <= 0) return;
    __shared__ int h[MAXBINW];
    int tid = threadIdx.x;
    for (int i = tid; i < width; i += 1024) h[i] = 0;
    __syncthreads();
    int cnt = B.binCnt[r * NBIN + bin];
    const uint2* st = B.staging[r] + B.binBase[r * NBIN + bin];
    for (int i = tid; i < cnt; i += 1024) atomicAdd(&h[(int)st[i].y - d0], 1);
    __syncthreads();
    for (int i = tid; i < ndst; i += 1024) B.deg[r][d0 + i] = h[i];
}

// per-(rel,bin) scatter with LDS curs (no global atomics); adj writes L2-resident
__global__ __launch_bounds__(1024) void k_binp2(BinPack B) {
    int r = blockIdx.y, bin = blockIdx.x;
    int sh = B.binshift[r];
    int width = 1 << sh;
    int d0 = bin << sh;
    int Nd = B.Nd[r];
    int ndst = Nd - d0;
    if (ndst > width) ndst = width;
    if (ndst <= 0) return;
    __shared__ int curs[MAXBINW];
    int tid = threadIdx.x;
    for (int i = tid; i < ndst; i += 1024) curs[i] = B.offs[r][d0 + i];
    __syncthreads();
    int cnt = B.binCnt[r * NBIN + bin];
    const uint2* st = B.staging[r] + B.binBase[r * NBIN + bin];
    int* adj = B.adj[r];
    for (int i = tid; i < cnt; i += 1024) {
        uint2 ed = st[i];
        int slot = atomicAdd(&curs[(int)ed.y - d0], 1);
        adj[slot] = (int)ed.x;
    }
}

// ================= CSR scans (deg -> offs) =================
struct ScanPack {
    int* deg[8];
    int* offs[8];
    int Nd[8];
};

__global__ void k_scan_part_all(ScanPack P, int* __restrict__ part_all) {
    int r = blockIdx.y;
    int N = P.Nd[r];
    if (blockIdx.x * 256 >= N) return;
    __shared__ int sh[256];
    int t = threadIdx.x, i = blockIdx.x * 256 + t;
    sh[t] = (i < N) ? P.deg[r][i] : 0;
    __syncthreads();
    for (int o = 128; o; o >>= 1) {
        if (t < o) sh[t] += sh[t + o];
        __syncthreads();
    }
    if (t == 0) part_all[r * 512 + blockIdx.x] = sh[0];
}
__global__ void k_scan_top_all(int* __restrict__ part_all, ScanPack P) {
    int r = blockIdx.x;
    int n = (P.Nd[r] + 255) / 256;
    __shared__ int sh[512];
    int t = threadIdx.x;
    int v = (t < n) ? part_all[r * 512 + t] : 0;
    sh[t] = v;
    __syncthreads();
    for (int o = 1; o < 512; o <<= 1) {
        int tmp = (t >= o) ? sh[t - o] : 0;
        __syncthreads();
        sh[t] += tmp;
        __syncthreads();
    }
    if (t < n) part_all[r * 512 + t] = sh[t] - v;
}
__global__ void k_scan_down_all(ScanPack P, const int* __restrict__ part_all) {
    int r = blockIdx.y;
    int N = P.Nd[r];
    if (blockIdx.x * 256 >= N) return;
    __shared__ int sh[256];
    int t = threadIdx.x, i = blockIdx.x * 256 + t;
    int v = (i < N) ? P.deg[r][i] : 0;
    sh[t] = v;
    __syncthreads();
    for (int o = 1; o < 256; o <<= 1) {
        int tmp = (t >= o) ? sh[t - o] : 0;
        __syncthreads();
        sh[t] += tmp;
        __syncthreads();
    }
    if (i < N) P.offs[r][i] = sh[t] - v + part_all[r * 512 + blockIdx.x];
}

// ================= fused mid pass: gemm || logits =================
__device__ __forceinline__ void gemm_body(char* smemraw, const float* __restrict__ A,
                                          const __hip_bfloat16* __restrict__ Bsw,
                                          __hip_bfloat16* __restrict__ out,
                                          int M, int Ncols, int bx, int by) {
    __hip_bfloat16 (*Alds)[136] = (__hip_bfloat16 (*)[136])smemraw;
    int m0 = bx * 64, n0 = by * 128;
    int t = threadIdx.x;
    for (int i = t; i < 2048; i += 256) {
        int row = i >> 5, ch = i & 31;
        float4 v = make_float4(0.f, 0.f, 0.f, 0.f);
        if (m0 + row < M) v = *(const float4*)(A + (size_t)(m0 + row) * 128 + ch * 4);
        __hip_bfloat16* dp = &Alds[row][ch * 4];
        dp[0] = __float2bfloat16(v.x);
        dp[1] = __float2bfloat16(v.y);
        dp[2] = __float2bfloat16(v.z);
        dp[3] = __float2bfloat16(v.w);
    }
    __syncthreads();
    int w = t >> 6, l = t & 63;
    int lane16 = l & 15, q = l >> 4;
    f32x4 acc[8];
#pragma unroll
    for (int nn = 0; nn < 8; ++nn) acc[nn] = (f32x4){0.f, 0.f, 0.f, 0.f};
    const __hip_bfloat16* arow = &Alds[w * 16 + lane16][q * 8];
#pragma unroll
    for (int kk = 0; kk < 4; ++kk) {
        bf16x8 a = *(const bf16x8*)(arow + kk * 32);
#pragma unroll
        for (int nn = 0; nn < 8; ++nn) {
            size_t boff = ((size_t)(kk * 4 + q) * Ncols + (n0 + nn * 16 + lane16)) * 8;
            bf16x8 b = *(const bf16x8*)(Bsw + boff);
            acc[nn] = __builtin_amdgcn_mfma_f32_16x16x32_bf16(a, b, acc[nn], 0, 0, 0);
        }
    }
    int orow = m0 + w * 16 + q * 4;
#pragma unroll
    for (int nn = 0; nn < 8; ++nn) {
        int col = n0 + nn * 16 + lane16;
#pragma unroll
        for (int r = 0; r < 4; ++r) {
            int row = orow + r;
            if (row < M) out[(size_t)row * Ncols + col] = __float2bfloat16(acc[nn][r]);
        }
    }
}

__device__ __forceinline__ void logits_body(char* smemraw,
                                            const float* const vec[7], float* const outp[7],
                                            const float* __restrict__ x, int N, int nv, int bloc) {
    float (*vs)[128][4] = (float (*)[128][4])smemraw;
    int t = threadIdx.x;
    for (int i = t; i < nv * 512; i += 256) {
        int v = i >> 9, j = i & 511;
        vs[v][j >> 2][j & 3] = vec[v][j];
    }
    __syncthreads();
    int nl = t >> 2, h = t & 3;
    int node = bloc * 64 + nl;
    if (node >= N) return;
    const float* xr = x + (size_t)node * 128;
    float acc[7];
#pragma unroll
    for (int v = 0; v < 7; ++v) acc[v] = 0.f;
#pragma unroll 4
    for (int k = 0; k < 128; ++k) {
        float xv = xr[k];
#pragma unroll
        for (int v = 0; v < 7; ++v)
            if (v < nv) acc[v] += xv * vs[v][k][h];
    }
#pragma unroll
    for (int v = 0; v < 7; ++v)
        if (v < nv) outp[v][node * 4 + h] = acc[v];
}

struct MidPack {
    const float* gA[3]; const __hip_bfloat16* gB[3]; __hip_bfloat16* gO[3];
    int gM[3]; int gNc[3]; int gMB[3]; int g_off[4];
    const float* lvec[4][7]; float* lout[4][7]; const float* lx[4];
    int lN[4]; int lnv[4]; int l_off[5];
};

__global__ __launch_bounds__(256) void k_mid(MidPack M) {
    __shared__ __align__(16) char smem[17408];
    int b = blockIdx.x;
    if (b < M.g_off[3]) {
#pragma unroll
        for (int g = 0; g < 3; ++g) {
            if (b >= M.g_off[g] && b < M.g_off[g + 1]) {
                int local = b - M.g_off[g];
                int bx = local % M.gMB[g];
                int by = local / M.gMB[g];
                gemm_body(smem, M.gA[g], M.gB[g], M.gO[g], M.gM[g], M.gNc[g], bx, by);
            }
        }
        return;
    }
    b -= M.g_off[3];
#pragma unroll
    for (int t = 0; t < 4; ++t) {
        if (b >= M.l_off[t] && b < M.l_off[t + 1]) {
            logits_body(smem, M.lvec[t], M.lout[t], M.lx[t], M.lN[t], M.lnv[t], b - M.l_off[t]);
        }
    }
}

// ================= fused per-dst GAT =================
struct RelArg {
    const __hip_bfloat16* hs;
    int hstride;
    int hoff;
    const float* als;
    const float* ald;
    const int* adj;
    const int* off;
    const int* deg;
    const float* bias;
};

__device__ __forceinline__ void dst_body(const RelArg& r0, const RelArg& r1, const RelArg& r2,
                                         int nrel, float inv_nrel, float* __restrict__ x,
                                         const float* __restrict__ ln_s,
                                         const float* __restrict__ ln_b, int N, int bloc) {
    int wv = threadIdx.x >> 6, lane = threadIdx.x & 63;
    int half = lane >> 5, sl = lane & 31;
    int d = bloc * 8 + wv * 2 + half;
    if (d >= N) return;
    int c0 = sl * 4;
    int h = sl >> 3;
    float4 xv = *(const float4*)&x[(size_t)d * HID + c0];
    float rel0 = 0.f, rel1 = 0.f, rel2 = 0.f, rel3 = 0.f;
    for (int rr = 0; rr < nrel; ++rr) {
        const RelArg& R = (rr == 0) ? r0 : (rr == 1) ? r1 : r2;
        int base = R.off[d];
        int dg = R.deg[d];
        float aldh = R.ald[d * NHEAD + h];
        const __hip_bfloat16* hp = R.hs + R.hoff + c0;
        const int hstr = R.hstride;
        const int* ap = R.adj + base;
        const float* als = R.als;
        float a0 = 0.f, a1 = 0.f, a2 = 0.f, a3 = 0.f, den = 0.f;
        int k = 0;
        for (; k + 4 <= dg; k += 4) {
            int s0 = ap[k], s1 = ap[k + 1], s2 = ap[k + 2], s3 = ap[k + 3];
            float w0 = __expf(lrelu(als[s0 * NHEAD + h] + aldh));
            float w1 = __expf(lrelu(als[s1 * NHEAD + h] + aldh));
            float w2 = __expf(lrelu(als[s2 * NHEAD + h] + aldh));
            float w3 = __expf(lrelu(als[s3 * NHEAD + h] + aldh));
            bf16x4s v0 = *(const bf16x4s*)(hp + (size_t)s0 * hstr);
            bf16x4s v1 = *(const bf16x4s*)(hp + (size_t)s1 * hstr);
            bf16x4s v2 = *(const bf16x4s*)(hp + (size_t)s2 * hstr);
            bf16x4s v3 = *(const bf16x4s*)(hp + (size_t)s3 * hstr);
            a0 += w0 * bf2f(v0[0]) + w1 * bf2f(v1[0]) + w2 * bf2f(v2[0]) + w3 * bf2f(v3[0]);
            a1 += w0 * bf2f(v0[1]) + w1 * bf2f(v1[1]) + w2 * bf2f(v2[1]) + w3 * bf2f(v3[1]);
            a2 += w0 * bf2f(v0[2]) + w1 * bf2f(v1[2]) + w2 * bf2f(v2[2]) + w3 * bf2f(v3[2]);
            a3 += w0 * bf2f(v0[3]) + w1 * bf2f(v1[3]) + w2 * bf2f(v2[3]) + w3 * bf2f(v3[3]);
            den += w0 + w1 + w2 + w3;
        }
        for (; k < dg; ++k) {
            int s = ap[k];
            float w = __expf(lrelu(als[s * NHEAD + h] + aldh));
            bf16x4s v = *(const bf16x4s*)(hp + (size_t)s * hstr);
            a0 += w * bf2f(v[0]);
            a1 += w * bf2f(v[1]);
            a2 += w * bf2f(v[2]);
            a3 += w * bf2f(v[3]);
            den += w;
        }
        float inv = 1.f / (den + 1e-16f);
        rel0 += a0 * inv + R.bias[c0];
        rel1 += a1 * inv + R.bias[c0 + 1];
        rel2 += a2 * inv + R.bias[c0 + 2];
        rel3 += a3 * inv + R.bias[c0 + 3];
    }
    float v0 = rel0 * inv_nrel, v1 = rel1 * inv_nrel;
    float v2 = rel2 * inv_nrel, v3 = rel3 * inv_nrel;
    v0 = (v0 > 0.f) ? v0 : 0.f;
    v1 = (v1 > 0.f) ? v1 : 0.f;
    v2 = (v2 > 0.f) ? v2 : 0.f;
    v3 = (v3 > 0.f) ? v3 : 0.f;
    v0 += xv.x; v1 += xv.y; v2 += xv.z; v3 += xv.w;
    float s = v0 + v1 + v2 + v3;
    float ss = v0 * v0 + v1 * v1 + v2 * v2 + v3 * v3;
#pragma unroll
    for (int o = 16; o; o >>= 1) {
        s += __shfl_xor(s, o);
        ss += __shfl_xor(ss, o);
    }
    float mu = s * (1.f / HID);
    float var = ss * (1.f / HID) - mu * mu;
    float rstd = rsqrtf(var + 1e-5f);
    float o0 = (v0 - mu) * rstd * ln_s[c0] + ln_b[c0];
    float o1 = (v1 - mu) * rstd * ln_s[c0 + 1] + ln_b[c0 + 1];
    float o2 = (v2 - mu) * rstd * ln_s[c0 + 2] + ln_b[c0 + 2];
    float o3 = (v3 - mu) * rstd * ln_s[c0 + 3] + ln_b[c0 + 3];
    *(float4*)&x[(size_t)d * HID + c0] = make_float4(o0, o1, o2, o3);
}

struct TypeArg {
    RelArg r0, r1, r2;
    float* x;
    int N;
    int nrel;
    float inv_nrel;
};

__global__ __launch_bounds__(256) void k_dst_all(TypeArg t0, TypeArg t1, TypeArg t2, TypeArg t3,
                                                 int off1, int off2, int off3,
                                                 const float* __restrict__ ln_s,
                                                 const float* __restrict__ ln_b) {
    int b = blockIdx.x;
    if (b < off1) {
        dst_body(t0.r0, t0.r1, t0.r2, t0.nrel, t0.inv_nrel, t0.x, ln_s, ln_b, t0.N, b);
    } else if (b < off2) {
        dst_body(t1.r0, t1.r1, t1.r2, t1.nrel, t1.inv_nrel, t1.x, ln_s, ln_b, t1.N, b - off1);
    } else if (b < off3) {
        dst_body(t2.r0, t2.r1, t2.r2, t2.nrel, t2.inv_nrel, t2.x, ln_s, ln_b, t2.N, b - off2);
    } else {
        dst_body(t3.r0, t3.r1, t3.r2, t3.nrel, t3.inv_nrel, t3.x, ln_s, ln_b, t3.N, b - off3);
    }
}

// ================= pooling =================
__global__ void k_pool_all(const float* __restrict__ x0, const float* __restrict__ x1,
                           const float* __restrict__ x2, const float* __restrict__ x3,
                           const int* __restrict__ b0, const int* __restrict__ b1,
                           const int* __restrict__ b2, const int* __restrict__ b3,
                           int N0, int N1, int N2, int N3, float* __restrict__ out) {
    int ty = blockIdx.y;
    const float* x;
    const int* b;
    int N, toff;
    if (ty == 0)      { x = x0; b = b0; N = N0; toff = 0; }
    else if (ty == 1) { x = x1; b = b1; N = N1; toff = 128; }
    else if (ty == 2) { x = x2; b = b2; N = N2; toff = 256; }
    else              { x = x3; b = b3; N = N3; toff = 384; }
    int r0 = blockIdx.x * PCHUNK;
    if (r0 >= N) return;
    int rend = min(r0 + PCHUNK, N);
    int c = threadIdx.x;
    int cur = b[r0];
    float acc = 0.f;
    for (int i = r0; i < rend; ++i) {
        int g = b[i];
        if (g != cur) {
            atomicAdd(&out[cur * 512 + toff + c], acc);
            acc = 0.f;
            cur = g;
        }
        acc += x[(size_t)i * HID + c];
    }
    atomicAdd(&out[cur * 512 + toff + c], acc);
}
__global__ void k_cnt(const int* __restrict__ b0, const int* __restrict__ b1,
                      const int* __restrict__ b2, const int* __restrict__ b3,
                      int N0, int N1, int N2, int N3, float* __restrict__ cnt) {
    int i = blockIdx.x * blockDim.x + threadIdx.x;
    if (i >= 256) return;
    int t = i >> 6, g = i & 63;
    const int* b = (t == 0) ? b0 : (t == 1) ? b1 : (t == 2) ? b2 : b3;
    int N = (t == 0) ? N0 : (t == 1) ? N1 : (t == 2) ? N2 : N3;
    int lo = 0, hi = N;
    while (lo < hi) { int m = (lo + hi) >> 1; if (b[m] < g) lo = m + 1; else hi = m; }
    int s = lo;
    hi = N;
    while (lo < hi) { int m = (lo + hi) >> 1; if (b[m] < g + 1) lo = m + 1; else hi = m; }
    cnt[i] = (float)(lo - s);
}
__global__ void k_div(float* __restrict__ out, const float* __restrict__ cnt) {
    int idx = blockIdx.x * blockDim.x + threadIdx.x;
    if (idx >= NGRAPH * 512) return;
    int g = idx >> 9, c = idx & 511, t = c >> 7;
    out[idx] = out[idx] / fmaxf(cnt[t * NGRAPH + g], 1.0f);
}

extern "C" void kernel_launch(void* const* d_in, const int* in_sizes, int n_in,
                              void* d_out, int out_size, void* d_ws, size_t ws_size,
                              hipStream_t stream) {
    const float* x_in[4] = {(const float*)d_in[0], (const float*)d_in[1],
                            (const float*)d_in[2], (const float*)d_in[3]};
    const float* Wp[4] = {(const float*)d_in[4], (const float*)d_in[6],
                          (const float*)d_in[8], (const float*)d_in[10]};
    const float* bp[4] = {(const float*)d_in[5], (const float*)d_in[7],
                          (const float*)d_in[9], (const float*)d_in[11]};
    const float* gat_W  = (const float*)d_in[12];
    const float* gat_as = (const float*)d_in[13];
    const float* gat_ad = (const float*)d_in[14];
    const float* gat_b  = (const float*)d_in[15];
    const float* ln_s   = (const float*)d_in[16];
    const float* ln_b   = (const float*)d_in[17];
    const int* esrc[8] = {(const int*)d_in[18], (const int*)d_in[20], (const int*)d_in[22],
                          (const int*)d_in[24], (const int*)d_in[26], (const int*)d_in[28],
                          (const int*)d_in[30], (const int*)d_in[32]};
    const int* edst[8] = {(const int*)d_in[19], (const int*)d_in[21], (const int*)d_in[23],
                          (const int*)d_in[25], (const int*)d_in[27], (const int*)d_in[29],
                          (const int*)d_in[31], (const int*)d_in[33]};
    const int* bidx[4] = {(const int*)d_in[34], (const int*)d_in[35],
                          (const int*)d_in[36], (const int*)d_in[37]};
    int E[8];
    {
        const int eidx[8] = {18, 20, 22, 24, 26, 28, 30, 32};
        for (int r = 0; r < 8; ++r) E[r] = in_sizes[eidx[r]];
    }
    const int Kin[4] = {8, 10, 7, 3};
    int N[4];
    for (int t = 0; t < 4; ++t) N[t] = in_sizes[t] / Kin[t];
    const int rel_st[8] = {0, 1, 0, 2, 0, 0, 1, 2};
    const int rel_dt[8] = {1, 0, 2, 0, 3, 0, 3, 3};
    const int rel_hoff[8] = {0, 0, 128, 0, 256, 384, 128, 128};
    const int grp_stride[4] = {512, 256, 256, 0};
    (void)ws_size; (void)n_in;

    // ---- workspace ----
    char* wbase = (char*)d_ws;
    size_t cur = 0;
    auto alloc = [&](size_t bytes) -> void* {
        void* p = wbase + cur;
        cur += (bytes + 15) & ~(size_t)15;
        return p;
    };
    float* x[4];
    for (int t = 0; t < 4; ++t) x[t] = (float*)alloc((size_t)N[t] * HID * 4);
    __hip_bfloat16* hs_g[3];
    hs_g[0] = (__hip_bfloat16*)alloc((size_t)N[0] * 512 * 2);
    hs_g[1] = (__hip_bfloat16*)alloc((size_t)N[1] * 256 * 2);
    hs_g[2] = (__hip_bfloat16*)alloc((size_t)N[2] * 256 * 2);
    __hip_bfloat16* Wsw = (__hip_bfloat16*)alloc((size_t)2 * 131072 * 2);
    float* vecall = (float*)alloc((size_t)2 * 16 * 512 * 4);
    float *als_[8], *ald_[8];
    int *deg[8], *offs[8], *adj[8];
    uint2* staging[8];
    for (int r = 0; r < 8; ++r) {
        int Ns = N[rel_st[r]], Nd = N[rel_dt[r]];
        als_[r] = (float*)alloc((size_t)Ns * NHEAD * 4);
        ald_[r] = (float*)alloc((size_t)Nd * NHEAD * 4);
        deg[r]  = (int*)alloc((size_t)Nd * 4);
        offs[r] = (int*)alloc((size_t)Nd * 4);
        adj[r]  = (int*)alloc((size_t)E[r] * 4);
        staging[r] = (uint2*)alloc((size_t)E[r] * 8);
    }
    int* part_all = (int*)alloc(8 * 512 * 4);
    int* binCnt   = (int*)alloc(8 * NBIN * 4);
    int* binBase  = (int*)alloc(8 * NBIN * 4);
    int* binCur   = (int*)alloc(8 * NBIN * 4);
    float* cntf   = (float*)alloc(256 * 4);

    // ---- packs ----
    BinPack BP;
    int NdMax = 0;
    for (int r = 0; r < 8; ++r) {
        BP.esrc[r] = esrc[r]; BP.edst[r] = edst[r];
        BP.staging[r] = staging[r];
        BP.adj[r] = adj[r]; BP.deg[r] = deg[r]; BP.offs[r] = offs[r];
        BP.E[r] = E[r]; BP.Nd[r] = N[rel_dt[r]];
        int sh = 5;
        while (((BP.Nd[r] - 1) >> sh) > (NBIN - 1)) ++sh;
        BP.binshift[r] = sh;
        if (BP.Nd[r] > NdMax) NdMax = BP.Nd[r];
    }
    BP.binCnt = binCnt; BP.binBase = binBase; BP.binCur = binCur;
    ScanPack SP;
    for (int r = 0; r < 8; ++r) { SP.deg[r] = deg[r]; SP.offs[r] = offs[r]; SP.Nd[r] = BP.Nd[r]; }

    // ---- 0a. memset binCnt + fused pre-pass ----
    hipMemsetAsync(binCnt, 0, 8 * NBIN * 4, stream);
    PrePack PA;
    {
        for (int r = 0; r < 8; ++r) { PA.edst[r] = edst[r]; PA.E[r] = E[r]; PA.bsh[r] = BP.binshift[r]; }
        PA.binCnt = binCnt;
        PA.h_off[0] = 0;
        for (int r = 0; r < 8; ++r) PA.h_off[r + 1] = PA.h_off[r] + (E[r] + 255) / 256;
        for (int t = 0; t < 4; ++t) {
            PA.px[t] = x_in[t]; PA.pW[t] = Wp[t]; PA.pb[t] = bp[t]; PA.po[t] = x[t];
            PA.pN[t] = N[t]; PA.pK[t] = Kin[t];
        }
        PA.p_off[0] = 0;
        for (int t = 0; t < 4; ++t) PA.p_off[t + 1] = PA.p_off[t] + (N[t] * HID + 255) / 256;
        PA.gat_W = gat_W; PA.Wsw = Wsw;
        PA.gat_as = gat_as; PA.gat_ad = gat_ad; PA.vecall = vecall;
        int total = PA.h_off[8] + PA.p_off[4] + 1024 + 64;
        k_pre<<<total, 256, 0, stream>>>(PA);
    }

    // ---- 0b. bin scan -> stage -> LDS hist -> scans -> LDS scatter ----
    {
        k_binscan2<<<1, 64, 0, stream>>>(BP);
        dim3 g1(512, 8);
        k_binp1<<<g1, 256, 0, stream>>>(BP);
        dim3 gb(NBIN, 8);
        k_binhist<<<gb, 1024, 0, stream>>>(BP);
        dim3 gn((NdMax + 255) / 256, 8);
        k_scan_part_all<<<gn, 256, 0, stream>>>(SP, part_all);
        k_scan_top_all<<<8, 512, 0, stream>>>(part_all, SP);
        k_scan_down_all<<<gn, 256, 0, stream>>>(SP, part_all);
        k_binp2<<<gb, 1024, 0, stream>>>(BP);
    }

    // ---- independent: counts + out zero ----
    hipMemsetAsync(d_out, 0, (size_t)out_size * 4, stream);
    k_cnt<<<1, 256, 0, stream>>>(bidx[0], bidx[1], bidx[2], bidx[3],
                                 N[0], N[1], N[2], N[3], cntf);

    // ---- layers ----
    const size_t g_woff[3] = {0, 65536, 98304};
    const int g_ncols[3] = {512, 256, 256};
    int nb[4];
    for (int t = 0; t < 4; ++t) nb[t] = (N[t] + 7) / 8;
    int doff1 = nb[0], doff2 = nb[0] + nb[1], doff3 = nb[0] + nb[1] + nb[2];
    int dtot = doff3 + nb[3];

    for (int l = 0; l < 2; ++l) {
        MidPack M;
        M.g_off[0] = 0;
        for (int g = 0; g < 3; ++g) {
            M.gA[g] = x[g];
            M.gB[g] = Wsw + (size_t)l * 131072 + g_woff[g];
            M.gO[g] = hs_g[g];
            M.gM[g] = N[g];
            M.gNc[g] = g_ncols[g];
            M.gMB[g] = (N[g] + 63) / 64;
            M.g_off[g + 1] = M.g_off[g] + M.gMB[g] * (g_ncols[g] / 128);
        }
        const float* vl = vecall + (size_t)l * 16 * 512;
        auto vvec = [&](int r, int side) { return vl + (size_t)(r * 2 + side) * 512; };
        for (int t = 0; t < 4; ++t)
            for (int v = 0; v < 7; ++v) { M.lvec[t][v] = vl; M.lout[t][v] = als_[0]; }
        M.lvec[0][0] = vvec(0, 0); M.lout[0][0] = als_[0];
        M.lvec[0][1] = vvec(2, 0); M.lout[0][1] = als_[2];
        M.lvec[0][2] = vvec(4, 0); M.lout[0][2] = als_[4];
        M.lvec[0][3] = vvec(5, 0); M.lout[0][3] = als_[5];
        M.lvec[0][4] = vvec(1, 1); M.lout[0][4] = ald_[1];
        M.lvec[0][5] = vvec(3, 1); M.lout[0][5] = ald_[3];
        M.lvec[0][6] = vvec(5, 1); M.lout[0][6] = ald_[5];
        M.lvec[1][0] = vvec(1, 0); M.lout[1][0] = als_[1];
        M.lvec[1][1] = vvec(6, 0); M.lout[1][1] = als_[6];
        M.lvec[1][2] = vvec(0, 1); M.lout[1][2] = ald_[0];
        M.lvec[2][0] = vvec(3, 0); M.lout[2][0] = als_[3];
        M.lvec[2][1] = vvec(7, 0); M.lout[2][1] = als_[7];
        M.lvec[2][2] = vvec(2, 1); M.lout[2][2] = ald_[2];
        M.lvec[3][0] = vvec(4, 1); M.lout[3][0] = ald_[4];
        M.lvec[3][1] = vvec(6, 1); M.lout[3][1] = ald_[6];
        M.lvec[3][2] = vvec(7, 1); M.lout[3][2] = ald_[7];
        const int lnv[4] = {7, 3, 3, 3};
        M.l_off[0] = 0;
        for (int t = 0; t < 4; ++t) {
            M.lx[t] = x[t]; M.lN[t] = N[t]; M.lnv[t] = lnv[t];
            M.l_off[t + 1] = M.l_off[t] + (N[t] + 63) / 64;
        }
        int total = M.g_off[3] + M.l_off[4];
        k_mid<<<total, 256, 0, stream>>>(M);

        auto mk = [&](int r) {
            RelArg a;
            int st = rel_st[r];
            a.hs = hs_g[st]; a.hstride = grp_stride[st]; a.hoff = rel_hoff[r];
            a.als = als_[r]; a.ald = ald_[r];
            a.adj = adj[r]; a.off = offs[r]; a.deg = deg[r];
            a.bias = gat_b + (size_t)(l * 8 + r) * HID;
            return a;
        };
        TypeArg T[4];
        const int trels[4][3] = {{1, 3, 5}, {0, 0, 0}, {2, 2, 2}, {4, 6, 7}};
        const int tnrel[4] = {3, 1, 1, 3};
        const float tinv[4] = {1.f / 3.f, 1.f, 1.f, 1.f / 3.f};
        for (int t = 0; t < 4; ++t) {
            T[t].r0 = mk(trels[t][0]);
            T[t].r1 = mk(trels[t][1]);
            T[t].r2 = mk(trels[t][2]);
            T[t].x = x[t];
            T[t].N = N[t];
            T[t].nrel = tnrel[t];
            T[t].inv_nrel = tinv[t];
        }
        k_dst_all<<<dtot, 256, 0, stream>>>(T[0], T[1], T[2], T[3], doff1, doff2, doff3,
                                            ln_s + l * HID, ln_b + l * HID);
    }

    // ---- pooling ----
    {
        int pmax = 0;
        for (int t = 0; t < 4; ++t) {
            int p = (N[t] + PCHUNK - 1) / PCHUNK;
            if (p > pmax) pmax = p;
        }
        dim3 gp(pmax, 4);
        k_pool_all<<<gp, 128, 0, stream>>>(x[0], x[1], x[2], x[3],
                                           bidx[0], bidx[1], bidx[2], bidx[3],
                                           N[0], N[1], N[2], N[3], (float*)d_out);
    }
    k_div<<<(NGRAPH * 512 + 255) / 256, 256, 0, stream>>>((float*)d_out, cntf);
}

// Round 17
// 1111.585 us; speedup vs baseline: 1.2469x; 1.0610x over previous
//
#include <hip/hip_runtime.h>
#include <hip/hip_bf16.h>
#include <cstdint>

#define HID 128
#define NHEAD 4
#define NGRAPH 64
#define PCHUNK 32
#define NBIN 64
#define MAXBINW 2048

typedef __attribute__((ext_vector_type(8))) short bf16x8;
typedef __attribute__((ext_vector_type(4))) short bf16x4s;
typedef __attribute__((ext_vector_type(4))) float f32x4;

__device__ __forceinline__ float bf2f(short u) {
    union { float f; unsigned int i; } c;
    c.i = ((unsigned int)(unsigned short)u) << 16;
    return c.f;
}
__device__ __forceinline__ float lrelu(float a) { return (a > 0.f) ? a : 0.2f * a; }

// ================= fused pre-pass: bincount + proj + castW + mkvec =================
struct PrePack {
    const int* edst[8]; int E[8]; int h_off[9]; int bsh[8];
    int* binCnt; // 8*NBIN
    const float* px[4]; const float* pW[4]; const float* pb[4]; float* po[4];
    int pN[4]; int pK[4]; int p_off[5];
    const float* gat_W; __hip_bfloat16* Wsw;
    const float* gat_as; const float* gat_ad; float* vecall;
};

__global__ __launch_bounds__(256) void k_pre(PrePack A) {
    int b = blockIdx.x;
    int tid = threadIdx.x;
    if (b < A.h_off[8]) {
        __shared__ int h64[NBIN];
        if (tid < NBIN) h64[tid] = 0;
        __syncthreads();
#pragma unroll
        for (int r = 0; r < 8; ++r) {
            if (b >= A.h_off[r] && b < A.h_off[r + 1]) {
                int e = (b - A.h_off[r]) * 256 + tid;
                if (e < A.E[r]) atomicAdd(&h64[A.edst[r][e] >> A.bsh[r]], 1);
                __syncthreads();
                if (tid < NBIN && h64[tid] > 0) atomicAdd(&A.binCnt[r * NBIN + tid], h64[tid]);
            }
        }
        return;
    }
    b -= A.h_off[8];
    if (b < A.p_off[4]) {
#pragma unroll
        for (int t = 0; t < 4; ++t) {
            if (b >= A.p_off[t] && b < A.p_off[t + 1]) {
                int idx = (b - A.p_off[t]) * 256 + tid;
                if (idx < A.pN[t] * HID) {
                    int row = idx >> 7, c = idx & 127;
                    int K = A.pK[t];
                    float acc = A.pb[t][c];
                    for (int k = 0; k < K; ++k) acc += A.px[t][row * K + k] * A.pW[t][k * HID + c];
                    A.po[t][idx] = acc;
                }
            }
        }
        return;
    }
    b -= A.p_off[4];
    if (b < 1024) {  // castW
        int idx = b * 256 + tid;
        int l = idx >> 17;
        int rem = idx & 131071;
        int k = rem >> 10;
        int gc = rem & 1023;
        int rel, n, gobase, Ncols;
        if (gc < 512) {
            int i = gc >> 7;
            rel = (i == 0) ? 0 : (i == 1) ? 2 : (i == 2) ? 4 : 5;
            n = gc; gobase = 0; Ncols = 512;
        } else if (gc < 768) {
            int c2 = gc - 512;
            rel = (c2 >> 7) ? 6 : 1;
            n = c2; gobase = 65536; Ncols = 256;
        } else {
            int c2 = gc - 768;
            rel = (c2 >> 7) ? 7 : 3;
            n = c2; gobase = 98304; Ncols = 256;
        }
        int nl = n & 127;
        float v = A.gat_W[(((size_t)l * 8 + rel) * 128 + k) * 128 + nl];
        size_t dst = (size_t)l * 131072 + gobase + ((size_t)(k >> 3) * Ncols + n) * 8 + (k & 7);
        A.Wsw[dst] = __float2bfloat16(v);
        return;
    }
    b -= 1024;
    {   // mkvec
        int idx = b * 256 + tid;
        if (idx < 16384) {
            int h = idx & 3, k = (idx >> 2) & 127, p = (idx >> 9) & 15, l = idx >> 13;
            int r = p >> 1, side = p & 1;
            const float* W = A.gat_W + (((size_t)l * 8 + r) * 128 + k) * 128;
            const float* a = (side ? A.gat_ad : A.gat_as) + ((size_t)l * 8 + r) * 128;
            float s = 0.f;
#pragma unroll
            for (int j = 0; j < 32; ++j) s += W[h * 32 + j] * a[h * 32 + j];
            A.vecall[((size_t)l * 16 + p) * 512 + k * 4 + h] = s;
        }
    }
}

// ================= binned CSR build (zero per-edge global atomics) =================
struct BinPack {
    const int* esrc[8]; const int* edst[8];
    uint2* staging[8];
    int* adj[8]; int* deg[8]; int* offs[8];
    int* binCnt; int* binBase; int* binCur;   // 8*NBIN ints each
    int E[8]; int Nd[8]; int binshift[8];
};

__global__ void k_binscan2(BinPack B) {
    int r = threadIdx.x;
    if (r >= 8) return;
    int run = 0;
    for (int b = 0; b < NBIN; ++b) {
        int c = B.binCnt[r * NBIN + b];
        B.binBase[r * NBIN + b] = run;
        B.binCur[r * NBIN + b] = run;
        run += c;
    }
}

// phase 1: stage edges bin-contiguously (block-reserved runs)
__global__ __launch_bounds__(256) void k_binp1(BinPack B) {
    int r = blockIdx.y;
    int E = B.E[r];
    int sh = B.binshift[r];
    __shared__ int h[NBIN], base[NBIN], rk[NBIN];
    int tid = threadIdx.x;
    for (int e0 = blockIdx.x * 256; e0 < E; e0 += gridDim.x * 256) {
        if (tid < NBIN) { h[tid] = 0; rk[tid] = 0; }
        __syncthreads();
        int e = e0 + tid;
        int valid = e < E;
        int src = 0, dst = 0, bin = 0;
        if (valid) {
            src = B.esrc[r][e];
            dst = B.edst[r][e];
            bin = dst >> sh;
            atomicAdd(&h[bin], 1);
        }
        __syncthreads();
        if (tid < NBIN && h[tid] > 0) base[tid] = atomicAdd(&B.binCur[r * NBIN + tid], h[tid]);
        __syncthreads();
        if (valid) {
            int pos = base[bin] + atomicAdd(&rk[bin], 1);
            B.staging[r][pos] = make_uint2((unsigned)src, (unsigned)dst);
        }
        __syncthreads();
    }
}

// per-(rel,bin) LDS histogram -> deg + offs (block prefix scan; binBase IS the CSR base)
__global__ __launch_bounds__(1024) void k_binhist(BinPack B) {
    int r = blockIdx.y, bin = blockIdx.x;
    int sh = B.binshift[r];
    int width = 1 << sh;
    int d0 = bin << sh;
    int Nd = B.Nd[r];
    int ndst = Nd - d0;
    if (ndst > width) ndst = width;
    if (ndst <= 0) return;
    __shared__ int h[MAXBINW];
    __shared__ int s2[1024];
    int tid = threadIdx.x;
    for (int i = tid; i < MAXBINW; i += 1024) h[i] = 0;
    __syncthreads();
    int cnt = B.binCnt[r * NBIN + bin];
    const uint2* st = B.staging[r] + B.binBase[r * NBIN + bin];
    for (int i = tid; i < cnt; i += 1024) atomicAdd(&h[(int)st[i].y - d0], 1);
    __syncthreads();
    for (int i = tid; i < ndst; i += 1024) B.deg[r][d0 + i] = h[i];
    // prefix scan over 2048 elements: pair sums + Hillis-Steele on 1024
    int pair = h[2 * tid] + h[2 * tid + 1];
    s2[tid] = pair;
    __syncthreads();
    for (int o = 1; o < 1024; o <<= 1) {
        int v = (tid >= o) ? s2[tid - o] : 0;
        __syncthreads();
        s2[tid] += v;
        __syncthreads();
    }
    int ebase = B.binBase[r * NBIN + bin];
    int excl = s2[tid] - pair;
    if (2 * tid < ndst)     B.offs[r][d0 + 2 * tid]     = ebase + excl;
    if (2 * tid + 1 < ndst) B.offs[r][d0 + 2 * tid + 1] = ebase + excl + h[2 * tid];
}

// per-(rel,bin) scatter with LDS curs (no global atomics); adj writes L2-resident
__global__ __launch_bounds__(1024) void k_binp2(BinPack B) {
    int r = blockIdx.y, bin = blockIdx.x;
    int sh = B.binshift[r];
    int width = 1 << sh;
    int d0 = bin << sh;
    int Nd = B.Nd[r];
    int ndst = Nd - d0;
    if (ndst > width) ndst = width;
    if (ndst <= 0) return;
    __shared__ int curs[MAXBINW];
    int tid = threadIdx.x;
    for (int i = tid; i < ndst; i += 1024) curs[i] = B.offs[r][d0 + i];
    __syncthreads();
    int cnt = B.binCnt[r * NBIN + bin];
    const uint2* st = B.staging[r] + B.binBase[r * NBIN + bin];
    int* adj = B.adj[r];
    for (int i = tid; i < cnt; i += 1024) {
        uint2 ed = st[i];
        int slot = atomicAdd(&curs[(int)ed.y - d0], 1);
        adj[slot] = (int)ed.x;
    }
}

// ================= fused mid pass: gemm (A-tile reused across column tiles) || logits =================
__device__ __forceinline__ void gemm_body(char* smemraw, const float* __restrict__ A,
                                          const __hip_bfloat16* __restrict__ Bsw,
                                          __hip_bfloat16* __restrict__ out,
                                          int M, int Ncols, int nby, int bx) {
    __hip_bfloat16 (*Alds)[136] = (__hip_bfloat16 (*)[136])smemraw;
    int m0 = bx * 64;
    int t = threadIdx.x;
    for (int i = t; i < 2048; i += 256) {
        int row = i >> 5, ch = i & 31;
        float4 v = make_float4(0.f, 0.f, 0.f, 0.f);
        if (m0 + row < M) v = *(const float4*)(A + (size_t)(m0 + row) * 128 + ch * 4);
        __hip_bfloat16* dp = &Alds[row][ch * 4];
        dp[0] = __float2bfloat16(v.x);
        dp[1] = __float2bfloat16(v.y);
        dp[2] = __float2bfloat16(v.z);
        dp[3] = __float2bfloat16(v.w);
    }
    __syncthreads();
    int w = t >> 6, l = t & 63;
    int lane16 = l & 15, q = l >> 4;
    const __hip_bfloat16* arow = &Alds[w * 16 + lane16][q * 8];
    bf16x8 areg[4];
#pragma unroll
    for (int kk = 0; kk < 4; ++kk) areg[kk] = *(const bf16x8*)(arow + kk * 32);
    int orow = m0 + w * 16 + q * 4;
    for (int by = 0; by < nby; ++by) {
        int n0 = by * 128;
        f32x4 acc[8];
#pragma unroll
        for (int nn = 0; nn < 8; ++nn) acc[nn] = (f32x4){0.f, 0.f, 0.f, 0.f};
#pragma unroll
        for (int kk = 0; kk < 4; ++kk) {
#pragma unroll
            for (int nn = 0; nn < 8; ++nn) {
                size_t boff = ((size_t)(kk * 4 + q) * Ncols + (n0 + nn * 16 + lane16)) * 8;
                bf16x8 b = *(const bf16x8*)(Bsw + boff);
                acc[nn] = __builtin_amdgcn_mfma_f32_16x16x32_bf16(areg[kk], b, acc[nn], 0, 0, 0);
            }
        }
#pragma unroll
        for (int nn = 0; nn < 8; ++nn) {
            int col = n0 + nn * 16 + lane16;
#pragma unroll
            for (int r = 0; r < 4; ++r) {
                int row = orow + r;
                if (row < M) out[(size_t)row * Ncols + col] = __float2bfloat16(acc[nn][r]);
            }
        }
    }
}

__device__ __forceinline__ void logits_body(char* smemraw,
                                            const float* const vec[7], float* const outp[7],
                                            const float* __restrict__ x, int N, int nv, int bloc) {
    float (*vs)[128][4] = (float (*)[128][4])smemraw;
    int t = threadIdx.x;
    for (int i = t; i < nv * 512; i += 256) {
        int v = i >> 9, j = i & 511;
        vs[v][j >> 2][j & 3] = vec[v][j];
    }
    __syncthreads();
    int nl = t >> 2, h = t & 3;
    int node = bloc * 64 + nl;
    if (node >= N) return;
    const float* xr = x + (size_t)node * 128;
    float acc[7];
#pragma unroll
    for (int v = 0; v < 7; ++v) acc[v] = 0.f;
#pragma unroll 4
    for (int k = 0; k < 128; ++k) {
        float xv = xr[k];
#pragma unroll
        for (int v = 0; v < 7; ++v)
            if (v < nv) acc[v] += xv * vs[v][k][h];
    }
#pragma unroll
    for (int v = 0; v < 7; ++v)
        if (v < nv) outp[v][node * 4 + h] = acc[v];
}

struct MidPack {
    const float* gA[3]; const __hip_bfloat16* gB[3]; __hip_bfloat16* gO[3];
    int gM[3]; int gNc[3]; int gNB[3]; int g_off[4];
    const float* lvec[4][7]; float* lout[4][7]; const float* lx[4];
    int lN[4]; int lnv[4]; int l_off[5];
};

__global__ __launch_bounds__(256) void k_mid(MidPack M) {
    __shared__ __align__(16) char smem[17408];
    int b = blockIdx.x;
    if (b < M.g_off[3]) {
#pragma unroll
        for (int g = 0; g < 3; ++g) {
            if (b >= M.g_off[g] && b < M.g_off[g + 1]) {
                gemm_body(smem, M.gA[g], M.gB[g], M.gO[g], M.gM[g], M.gNc[g], M.gNB[g],
                          b - M.g_off[g]);
            }
        }
        return;
    }
    b -= M.g_off[3];
#pragma unroll
    for (int t = 0; t < 4; ++t) {
        if (b >= M.l_off[t] && b < M.l_off[t + 1]) {
            logits_body(smem, M.lvec[t], M.lout[t], M.lx[t], M.lN[t], M.lnv[t], b - M.l_off[t]);
        }
    }
}

// ================= fused per-dst GAT =================
struct RelArg {
    const __hip_bfloat16* hs;
    int hstride;
    int hoff;
    const float* als;
    const float* ald;
    const int* adj;
    const int* off;
    const int* deg;
    const float* bias;
};

__device__ __forceinline__ void dst_body(const RelArg& r0, const RelArg& r1, const RelArg& r2,
                                         int nrel, float inv_nrel, float* __restrict__ x,
                                         const float* __restrict__ ln_s,
                                         const float* __restrict__ ln_b, int N, int bloc) {
    int wv = threadIdx.x >> 6, lane = threadIdx.x & 63;
    int half = lane >> 5, sl = lane & 31;
    int d = bloc * 8 + wv * 2 + half;
    if (d >= N) return;
    int c0 = sl * 4;
    int h = sl >> 3;
    float4 xv = *(const float4*)&x[(size_t)d * HID + c0];
    float rel0 = 0.f, rel1 = 0.f, rel2 = 0.f, rel3 = 0.f;
    for (int rr = 0; rr < nrel; ++rr) {
        const RelArg& R = (rr == 0) ? r0 : (rr == 1) ? r1 : r2;
        int base = R.off[d];
        int dg = R.deg[d];
        float aldh = R.ald[d * NHEAD + h];
        const __hip_bfloat16* hp = R.hs + R.hoff + c0;
        const int hstr = R.hstride;
        const int* ap = R.adj + base;
        const float* als = R.als;
        float a0 = 0.f, a1 = 0.f, a2 = 0.f, a3 = 0.f, den = 0.f;
        int k = 0;
        for (; k + 4 <= dg; k += 4) {
            int s0 = ap[k], s1 = ap[k + 1], s2 = ap[k + 2], s3 = ap[k + 3];
            float w0 = __expf(lrelu(als[s0 * NHEAD + h] + aldh));
            float w1 = __expf(lrelu(als[s1 * NHEAD + h] + aldh));
            float w2 = __expf(lrelu(als[s2 * NHEAD + h] + aldh));
            float w3 = __expf(lrelu(als[s3 * NHEAD + h] + aldh));
            bf16x4s v0 = *(const bf16x4s*)(hp + (size_t)s0 * hstr);
            bf16x4s v1 = *(const bf16x4s*)(hp + (size_t)s1 * hstr);
            bf16x4s v2 = *(const bf16x4s*)(hp + (size_t)s2 * hstr);
            bf16x4s v3 = *(const bf16x4s*)(hp + (size_t)s3 * hstr);
            a0 += w0 * bf2f(v0[0]) + w1 * bf2f(v1[0]) + w2 * bf2f(v2[0]) + w3 * bf2f(v3[0]);
            a1 += w0 * bf2f(v0[1]) + w1 * bf2f(v1[1]) + w2 * bf2f(v2[1]) + w3 * bf2f(v3[1]);
            a2 += w0 * bf2f(v0[2]) + w1 * bf2f(v1[2]) + w2 * bf2f(v2[2]) + w3 * bf2f(v3[2]);
            a3 += w0 * bf2f(v0[3]) + w1 * bf2f(v1[3]) + w2 * bf2f(v2[3]) + w3 * bf2f(v3[3]);
            den += w0 + w1 + w2 + w3;
        }
        for (; k < dg; ++k) {
            int s = ap[k];
            float w = __expf(lrelu(als[s * NHEAD + h] + aldh));
            bf16x4s v = *(const bf16x4s*)(hp + (size_t)s * hstr);
            a0 += w * bf2f(v[0]);
            a1 += w * bf2f(v[1]);
            a2 += w * bf2f(v[2]);
            a3 += w * bf2f(v[3]);
            den += w;
        }
        float inv = 1.f / (den + 1e-16f);
        rel0 += a0 * inv + R.bias[c0];
        rel1 += a1 * inv + R.bias[c0 + 1];
        rel2 += a2 * inv + R.bias[c0 + 2];
        rel3 += a3 * inv + R.bias[c0 + 3];
    }
    float v0 = rel0 * inv_nrel, v1 = rel1 * inv_nrel;
    float v2 = rel2 * inv_nrel, v3 = rel3 * inv_nrel;
    v0 = (v0 > 0.f) ? v0 : 0.f;
    v1 = (v1 > 0.f) ? v1 : 0.f;
    v2 = (v2 > 0.f) ? v2 : 0.f;
    v3 = (v3 > 0.f) ? v3 : 0.f;
    v0 += xv.x; v1 += xv.y; v2 += xv.z; v3 += xv.w;
    float s = v0 + v1 + v2 + v3;
    float ss = v0 * v0 + v1 * v1 + v2 * v2 + v3 * v3;
#pragma unroll
    for (int o = 16; o; o >>= 1) {
        s += __shfl_xor(s, o);
        ss += __shfl_xor(ss, o);
    }
    float mu = s * (1.f / HID);
    float var = ss * (1.f / HID) - mu * mu;
    float rstd = rsqrtf(var + 1e-5f);
    float o0 = (v0 - mu) * rstd * ln_s[c0] + ln_b[c0];
    float o1 = (v1 - mu) * rstd * ln_s[c0 + 1] + ln_b[c0 + 1];
    float o2 = (v2 - mu) * rstd * ln_s[c0 + 2] + ln_b[c0 + 2];
    float o3 = (v3 - mu) * rstd * ln_s[c0 + 3] + ln_b[c0 + 3];
    *(float4*)&x[(size_t)d * HID + c0] = make_float4(o0, o1, o2, o3);
}

struct TypeArg {
    RelArg r0, r1, r2;
    float* x;
    int N;
    int nrel;
    float inv_nrel;
};

__global__ __launch_bounds__(256) void k_dst_all(TypeArg t0, TypeArg t1, TypeArg t2, TypeArg t3,
                                                 int off1, int off2, int off3,
                                                 const float* __restrict__ ln_s,
                                                 const float* __restrict__ ln_b) {
    int b = blockIdx.x;
    if (b < off1) {
        dst_body(t0.r0, t0.r1, t0.r2, t0.nrel, t0.inv_nrel, t0.x, ln_s, ln_b, t0.N, b);
    } else if (b < off2) {
        dst_body(t1.r0, t1.r1, t1.r2, t1.nrel, t1.inv_nrel, t1.x, ln_s, ln_b, t1.N, b - off1);
    } else if (b < off3) {
        dst_body(t2.r0, t2.r1, t2.r2, t2.nrel, t2.inv_nrel, t2.x, ln_s, ln_b, t2.N, b - off2);
    } else {
        dst_body(t3.r0, t3.r1, t3.r2, t3.nrel, t3.inv_nrel, t3.x, ln_s, ln_b, t3.N, b - off3);
    }
}

// ================= pooling =================
__global__ void k_pool_all(const float* __restrict__ x0, const float* __restrict__ x1,
                           const float* __restrict__ x2, const float* __restrict__ x3,
                           const int* __restrict__ b0, const int* __restrict__ b1,
                           const int* __restrict__ b2, const int* __restrict__ b3,
                           int N0, int N1, int N2, int N3, float* __restrict__ out) {
    int ty = blockIdx.y;
    const float* x;
    const int* b;
    int N, toff;
    if (ty == 0)      { x = x0; b = b0; N = N0; toff = 0; }
    else if (ty == 1) { x = x1; b = b1; N = N1; toff = 128; }
    else if (ty == 2) { x = x2; b = b2; N = N2; toff = 256; }
    else              { x = x3; b = b3; N = N3; toff = 384; }
    int r0 = blockIdx.x * PCHUNK;
    if (r0 >= N) return;
    int rend = min(r0 + PCHUNK, N);
    int c = threadIdx.x;
    int cur = b[r0];
    float acc = 0.f;
    for (int i = r0; i < rend; ++i) {
        int g = b[i];
        if (g != cur) {
            atomicAdd(&out[cur * 512 + toff + c], acc);
            acc = 0.f;
            cur = g;
        }
        acc += x[(size_t)i * HID + c];
    }
    atomicAdd(&out[cur * 512 + toff + c], acc);
}
__global__ void k_cnt(const int* __restrict__ b0, const int* __restrict__ b1,
                      const int* __restrict__ b2, const int* __restrict__ b3,
                      int N0, int N1, int N2, int N3, float* __restrict__ cnt) {
    int i = blockIdx.x * blockDim.x + threadIdx.x;
    if (i >= 256) return;
    int t = i >> 6, g = i & 63;
    const int* b = (t == 0) ? b0 : (t == 1) ? b1 : (t == 2) ? b2 : b3;
    int N = (t == 0) ? N0 : (t == 1) ? N1 : (t == 2) ? N2 : N3;
    int lo = 0, hi = N;
    while (lo < hi) { int m = (lo + hi) >> 1; if (b[m] < g) lo = m + 1; else hi = m; }
    int s = lo;
    hi = N;
    while (lo < hi) { int m = (lo + hi) >> 1; if (b[m] < g + 1) lo = m + 1; else hi = m; }
    cnt[i] = (float)(lo - s);
}
__global__ void k_div(float* __restrict__ out, const float* __restrict__ cnt) {
    int idx = blockIdx.x * blockDim.x + threadIdx.x;
    if (idx >= NGRAPH * 512) return;
    int g = idx >> 9, c = idx & 511, t = c >> 7;
    out[idx] = out[idx] / fmaxf(cnt[t * NGRAPH + g], 1.0f);
}

extern "C" void kernel_launch(void* const* d_in, const int* in_sizes, int n_in,
                              void* d_out, int out_size, void* d_ws, size_t ws_size,
                              hipStream_t stream) {
    const float* x_in[4] = {(const float*)d_in[0], (const float*)d_in[1],
                            (const float*)d_in[2], (const float*)d_in[3]};
    const float* Wp[4] = {(const float*)d_in[4], (const float*)d_in[6],
                          (const float*)d_in[8], (const float*)d_in[10]};
    const float* bp[4] = {(const float*)d_in[5], (const float*)d_in[7],
                          (const float*)d_in[9], (const float*)d_in[11]};
    const float* gat_W  = (const float*)d_in[12];
    const float* gat_as = (const float*)d_in[13];
    const float* gat_ad = (const float*)d_in[14];
    const float* gat_b  = (const float*)d_in[15];
    const float* ln_s   = (const float*)d_in[16];
    const float* ln_b   = (const float*)d_in[17];
    const int* esrc[8] = {(const int*)d_in[18], (const int*)d_in[20], (const int*)d_in[22],
                          (const int*)d_in[24], (const int*)d_in[26], (const int*)d_in[28],
                          (const int*)d_in[30], (const int*)d_in[32]};
    const int* edst[8] = {(const int*)d_in[19], (const int*)d_in[21], (const int*)d_in[23],
                          (const int*)d_in[25], (const int*)d_in[27], (const int*)d_in[29],
                          (const int*)d_in[31], (const int*)d_in[33]};
    const int* bidx[4] = {(const int*)d_in[34], (const int*)d_in[35],
                          (const int*)d_in[36], (const int*)d_in[37]};
    int E[8];
    {
        const int eidx[8] = {18, 20, 22, 24, 26, 28, 30, 32};
        for (int r = 0; r < 8; ++r) E[r] = in_sizes[eidx[r]];
    }
    const int Kin[4] = {8, 10, 7, 3};
    int N[4];
    for (int t = 0; t < 4; ++t) N[t] = in_sizes[t] / Kin[t];
    const int rel_st[8] = {0, 1, 0, 2, 0, 0, 1, 2};
    const int rel_dt[8] = {1, 0, 2, 0, 3, 0, 3, 3};
    const int rel_hoff[8] = {0, 0, 128, 0, 256, 384, 128, 128};
    const int grp_stride[4] = {512, 256, 256, 0};
    (void)ws_size; (void)n_in;

    // ---- workspace ----
    char* wbase = (char*)d_ws;
    size_t cur = 0;
    auto alloc = [&](size_t bytes) -> void* {
        void* p = wbase + cur;
        cur += (bytes + 15) & ~(size_t)15;
        return p;
    };
    float* x[4];
    for (int t = 0; t < 4; ++t) x[t] = (float*)alloc((size_t)N[t] * HID * 4);
    __hip_bfloat16* hs_g[3];
    hs_g[0] = (__hip_bfloat16*)alloc((size_t)N[0] * 512 * 2);
    hs_g[1] = (__hip_bfloat16*)alloc((size_t)N[1] * 256 * 2);
    hs_g[2] = (__hip_bfloat16*)alloc((size_t)N[2] * 256 * 2);
    __hip_bfloat16* Wsw = (__hip_bfloat16*)alloc((size_t)2 * 131072 * 2);
    float* vecall = (float*)alloc((size_t)2 * 16 * 512 * 4);
    float *als_[8], *ald_[8];
    int *deg[8], *offs[8], *adj[8];
    uint2* staging[8];
    for (int r = 0; r < 8; ++r) {
        int Ns = N[rel_st[r]], Nd = N[rel_dt[r]];
        als_[r] = (float*)alloc((size_t)Ns * NHEAD * 4);
        ald_[r] = (float*)alloc((size_t)Nd * NHEAD * 4);
        deg[r]  = (int*)alloc((size_t)Nd * 4);
        offs[r] = (int*)alloc((size_t)Nd * 4);
        adj[r]  = (int*)alloc((size_t)E[r] * 4);
        staging[r] = (uint2*)alloc((size_t)E[r] * 8);
    }
    int* binCnt   = (int*)alloc(8 * NBIN * 4);
    int* binBase  = (int*)alloc(8 * NBIN * 4);
    int* binCur   = (int*)alloc(8 * NBIN * 4);
    float* cntf   = (float*)alloc(256 * 4);

    // ---- packs ----
    BinPack BP;
    for (int r = 0; r < 8; ++r) {
        BP.esrc[r] = esrc[r]; BP.edst[r] = edst[r];
        BP.staging[r] = staging[r];
        BP.adj[r] = adj[r]; BP.deg[r] = deg[r]; BP.offs[r] = offs[r];
        BP.E[r] = E[r]; BP.Nd[r] = N[rel_dt[r]];
        int sh = 5;
        while (((BP.Nd[r] - 1) >> sh) > (NBIN - 1)) ++sh;
        BP.binshift[r] = sh;
    }
    BP.binCnt = binCnt; BP.binBase = binBase; BP.binCur = binCur;

    // ---- 0a. memset binCnt + fused pre-pass ----
    hipMemsetAsync(binCnt, 0, 8 * NBIN * 4, stream);
    PrePack PA;
    {
        for (int r = 0; r < 8; ++r) { PA.edst[r] = edst[r]; PA.E[r] = E[r]; PA.bsh[r] = BP.binshift[r]; }
        PA.binCnt = binCnt;
        PA.h_off[0] = 0;
        for (int r = 0; r < 8; ++r) PA.h_off[r + 1] = PA.h_off[r] + (E[r] + 255) / 256;
        for (int t = 0; t < 4; ++t) {
            PA.px[t] = x_in[t]; PA.pW[t] = Wp[t]; PA.pb[t] = bp[t]; PA.po[t] = x[t];
            PA.pN[t] = N[t]; PA.pK[t] = Kin[t];
        }
        PA.p_off[0] = 0;
        for (int t = 0; t < 4; ++t) PA.p_off[t + 1] = PA.p_off[t] + (N[t] * HID + 255) / 256;
        PA.gat_W = gat_W; PA.Wsw = Wsw;
        PA.gat_as = gat_as; PA.gat_ad = gat_ad; PA.vecall = vecall;
        int total = PA.h_off[8] + PA.p_off[4] + 1024 + 64;
        k_pre<<<total, 256, 0, stream>>>(PA);
    }

    // ---- 0b. bin scan -> stage -> hist(+offs) -> LDS scatter ----
    {
        k_binscan2<<<1, 64, 0, stream>>>(BP);
        dim3 g1(512, 8);
        k_binp1<<<g1, 256, 0, stream>>>(BP);
        dim3 gb(NBIN, 8);
        k_binhist<<<gb, 1024, 0, stream>>>(BP);
        k_binp2<<<gb, 1024, 0, stream>>>(BP);
    }

    // ---- independent: counts + out zero ----
    hipMemsetAsync(d_out, 0, (size_t)out_size * 4, stream);
    k_cnt<<<1, 256, 0, stream>>>(bidx[0], bidx[1], bidx[2], bidx[3],
                                 N[0], N[1], N[2], N[3], cntf);

    // ---- layers ----
    const size_t g_woff[3] = {0, 65536, 98304};
    const int g_ncols[3] = {512, 256, 256};
    int nb[4];
    for (int t = 0; t < 4; ++t) nb[t] = (N[t] + 7) / 8;
    int doff1 = nb[0], doff2 = nb[0] + nb[1], doff3 = nb[0] + nb[1] + nb[2];
    int dtot = doff3 + nb[3];

    for (int l = 0; l < 2; ++l) {
        MidPack M;
        M.g_off[0] = 0;
        for (int g = 0; g < 3; ++g) {
            M.gA[g] = x[g];
            M.gB[g] = Wsw + (size_t)l * 131072 + g_woff[g];
            M.gO[g] = hs_g[g];
            M.gM[g] = N[g];
            M.gNc[g] = g_ncols[g];
            M.gNB[g] = g_ncols[g] / 128;
            M.g_off[g + 1] = M.g_off[g] + (N[g] + 63) / 64;
        }
        const float* vl = vecall + (size_t)l * 16 * 512;
        auto vvec = [&](int r, int side) { return vl + (size_t)(r * 2 + side) * 512; };
        for (int t = 0; t < 4; ++t)
            for (int v = 0; v < 7; ++v) { M.lvec[t][v] = vl; M.lout[t][v] = als_[0]; }
        M.lvec[0][0] = vvec(0, 0); M.lout[0][0] = als_[0];
        M.lvec[0][1] = vvec(2, 0); M.lout[0][1] = als_[2];
        M.lvec[0][2] = vvec(4, 0); M.lout[0][2] = als_[4];
        M.lvec[0][3] = vvec(5, 0); M.lout[0][3] = als_[5];
        M.lvec[0][4] = vvec(1, 1); M.lout[0][4] = ald_[1];
        M.lvec[0][5] = vvec(3, 1); M.lout[0][5] = ald_[3];
        M.lvec[0][6] = vvec(5, 1); M.lout[0][6] = ald_[5];
        M.lvec[1][0] = vvec(1, 0); M.lout[1][0] = als_[1];
        M.lvec[1][1] = vvec(6, 0); M.lout[1][1] = als_[6];
        M.lvec[1][2] = vvec(0, 1); M.lout[1][2] = ald_[0];
        M.lvec[2][0] = vvec(3, 0); M.lout[2][0] = als_[3];
        M.lvec[2][1] = vvec(7, 0); M.lout[2][1] = als_[7];
        M.lvec[2][2] = vvec(2, 1); M.lout[2][2] = ald_[2];
        M.lvec[3][0] = vvec(4, 1); M.lout[3][0] = ald_[4];
        M.lvec[3][1] = vvec(6, 1); M.lout[3][1] = ald_[6];
        M.lvec[3][2] = vvec(7, 1); M.lout[3][2] = ald_[7];
        const int lnv[4] = {7, 3, 3, 3};
        M.l_off[0] = 0;
        for (int t = 0; t < 4; ++t) {
            M.lx[t] = x[t]; M.lN[t] = N[t]; M.lnv[t] = lnv[t];
            M.l_off[t + 1] = M.l_off[t] + (N[t] + 63) / 64;
        }
        int total = M.g_off[3] + M.l_off[4];
        k_mid<<<total, 256, 0, stream>>>(M);

        auto mk = [&](int r) {
            RelArg a;
            int st = rel_st[r];
            a.hs = hs_g[st]; a.hstride = grp_stride[st]; a.hoff = rel_hoff[r];
            a.als = als_[r]; a.ald = ald_[r];
            a.adj = adj[r]; a.off = offs[r]; a.deg = deg[r];
            a.bias = gat_b + (size_t)(l * 8 + r) * HID;
            return a;
        };
        TypeArg T[4];
        const int trels[4][3] = {{1, 3, 5}, {0, 0, 0}, {2, 2, 2}, {4, 6, 7}};
        const int tnrel[4] = {3, 1, 1, 3};
        const float tinv[4] = {1.f / 3.f, 1.f, 1.f, 1.f / 3.f};
        for (int t = 0; t < 4; ++t) {
            T[t].r0 = mk(trels[t][0]);
            T[t].r1 = mk(trels[t][1]);
            T[t].r2 = mk(trels[t][2]);
            T[t].x = x[t];
            T[t].N = N[t];
            T[t].nrel = tnrel[t];
            T[t].inv_nrel = tinv[t];
        }
        k_dst_all<<<dtot, 256, 0, stream>>>(T[0], T[1], T[2], T[3], doff1, doff2, doff3,
                                            ln_s + l * HID, ln_b + l * HID);
    }

    // ---- pooling ----
    {
        int pmax = 0;
        for (int t = 0; t < 4; ++t) {
            int p = (N[t] + PCHUNK - 1) / PCHUNK;
            if (p > pmax) pmax = p;
        }
        dim3 gp(pmax, 4);
        k_pool_all<<<gp, 128, 0, stream>>>(x[0], x[1], x[2], x[3],
                                           bidx[0], bidx[1], bidx[2], bidx[3],
                                           N[0], N[1], N[2], N[3], (float*)d_out);
    }
    k_div<<<(NGRAPH * 512 + 255) / 256, 256, 0, stream>>>((float*)d_out, cntf);
}